// Round 6
// baseline (2406.651 us; speedup 1.0000x reference)
//
#include <hip/hip_runtime.h>
#include <hip/hip_bf16.h>
#include <math.h>

#define BB 32
#define TT 128
#define TD 127
#define EMB 256
#define HID 512
#define G4 2048
#define NV 10000
#define NB 64
#define UPB 8      // units per block -> 32 gate cols
#define NT_STEPS (TT + TD)

typedef __attribute__((ext_vector_type(8))) short short8v;
typedef __attribute__((ext_vector_type(4))) float f32x4;

__device__ __forceinline__ unsigned short bf16_rne(float x){
    unsigned int u = __float_as_uint(x);
    u += 0x7fffu + ((u >> 16) & 1u);
    return (unsigned short)(u >> 16);
}
__device__ __forceinline__ float bf16f(unsigned short h){
    return __uint_as_float(((unsigned int)h) << 16);
}

// ---------------- GEMM: X[t][col][b] = embed[tok] @ W + bias ----------------
__global__ __launch_bounds__(256) void gemm_x(const int* __restrict__ ids,
        const float* __restrict__ embed, const float* __restrict__ W,
        const float* __restrict__ bias, float* __restrict__ X, int M)
{
    __shared__ float As[16][128];
    __shared__ float Bs[16][128];
    __shared__ int toks[128];
    const int tid = threadIdx.x;
    const int m0 = blockIdx.y * 128, n0 = blockIdx.x * 128;
    if (tid < 128) {
        int mr = m0 + tid, tk = 0;
        if (mr < M) { int t = mr >> 5, b = mr & 31; tk = ids[b*TT + t]; }
        toks[tid] = tk;
    }
    __syncthreads();
    float acc[8][8] = {};
    const int ty = tid >> 4, tx = tid & 15;
    for (int kt = 0; kt < EMB; kt += 16) {
        #pragma unroll
        for (int i = 0; i < 2; i++) {
            int idx = tid*2 + i;
            int row = idx >> 2, k4 = (idx & 3)*4;
            float4 a = *(const float4*)&embed[(size_t)toks[row]*EMB + kt + k4];
            As[k4+0][row] = a.x; As[k4+1][row] = a.y; As[k4+2][row] = a.z; As[k4+3][row] = a.w;
        }
        #pragma unroll
        for (int i = 0; i < 2; i++) {
            int idx = tid*2 + i;
            int kr = idx >> 5, c4 = (idx & 31)*4;
            *(float4*)&Bs[kr][c4] = *(const float4*)&W[(size_t)(kt+kr)*G4 + n0 + c4];
        }
        __syncthreads();
        #pragma unroll
        for (int k = 0; k < 16; k++) {
            float a8[8], b8[8];
            #pragma unroll
            for (int i = 0; i < 8; i++) a8[i] = As[k][ty*8+i];
            #pragma unroll
            for (int j = 0; j < 8; j++) b8[j] = Bs[k][tx*8+j];
            #pragma unroll
            for (int i = 0; i < 8; i++) {
                #pragma unroll
                for (int j = 0; j < 8; j++)
                    acc[i][j] = fmaf(a8[i], b8[j], acc[i][j]);
            }
        }
        __syncthreads();
    }
    #pragma unroll
    for (int i = 0; i < 8; i++) {
        int mr = m0 + ty*8 + i;
        if (mr < M) {
            int tt = mr >> 5, bb2 = mr & 31;
            #pragma unroll
            for (int j = 0; j < 8; j++) {
                int nc = n0 + tx*8 + j;
                X[((size_t)tt*G4 + nc)*BB + bb2] = acc[i][j] + bias[nc];
            }
        }
    }
}

// ---------------- Persistent MFMA LSTM, tag-fused sync ----------------
// 64 blocks x 576 thr (9 waves). Waves 0-7: MFMA over K-slice [64w,64w+64);
// wave 8: X staging only (its HBM loads never join MFMA waves' vmcnt).
// h exchange: u64 words (tag<<32 | bf16hi | bf16lo<<16) in a 3-deep rotating
// buffer h_tag[3][512][32]. Consumers poll their own operand words until
// tag==g: detect+data = one L3 visit; producers never drain stores.
// In-loop barriers are raw lgkmcnt(0)+s_barrier (no vmcnt drains in loop).
__global__ __launch_bounds__(576) void lstm_persist(
        const float* __restrict__ Xenc, const float* __restrict__ Xdec,
        const float* __restrict__ Whh_e, const float* __restrict__ Whh_d,
        unsigned long long* __restrict__ h_tag,   // [3][512][32]
        float* __restrict__ hs)                   // [127][32][512]
{
    __shared__ float smem[11328];
    float* partials = smem;            // [8][32][36] (also W-stage scratch)
    float* xbuf     = smem + 9216;     // [2][32][33]

    const int tid = threadIdx.x;
    const int bid = blockIdx.x;
    const int u0  = bid*UPB;
    const int w   = tid >> 6;
    const int l   = tid & 63;
    const int rl  = l & 15;            // A-row / B-col / C-col in tile
    const int kg  = (l >> 4) * 8;      // frag k sub-base
    const int r4  = (l >> 4) * 4;      // C row base
    const int gb  = tid >> 3, gul = tid & 7;   // gate mapping (tid<256)

    short8v eH00,eH01,eH10,eH11, eL00,eL01,eL10,eL11;   // enc: [H|L][ntile][khalf]
    short8v dH00,dH01,dH10,dH11, dL00,dL01,dL10,dL11;   // dec

    #define BW(WH, WL, KB, CO) do { _Pragma("unroll") \
        for (int j = 0; j < 8; ++j) { \
            float wv = partials[((KB)+j)*32 + (CO) + rl]; \
            unsigned short htop = bf16_rne(wv); \
            WH[j] = (short)htop; \
            WL[j] = (short)bf16_rne(wv - bf16f(htop)); \
        } } while(0)

    #define STAGEB(SRC, H00,H01,H10,H11, L00,L01,L10,L11) do { \
        for (int c = 0; c < 4; ++c) { \
            __syncthreads(); \
            for (int i = tid; i < 4096; i += 576) { \
                int kl = i >> 5, n = i & 31; \
                partials[kl*32 + n] = SRC[(size_t)(c*128 + kl)*G4 + (size_t)((n>>3)*512 + u0 + (n&7))]; \
            } \
            __syncthreads(); \
            if (w < 8 && (w >> 1) == c) { \
                int kb0 = 64*(w & 1) + kg; \
                BW(H00, L00, kb0,      0); \
                BW(H01, L01, kb0 + 32, 0); \
                BW(H10, L10, kb0,     16); \
                BW(H11, L11, kb0 + 32,16); \
            } \
        } } while(0)

    STAGEB(Whh_e, eH00,eH01,eH10,eH11, eL00,eL01,eL10,eL11);
    STAGEB(Whh_d, dH00,dH01,dH10,dH11, dL00,dL01,dL10,dL11);

    // prologue: h(0)=0 tagged 0 for this block's units; stage X(0)
    if (tid < 256)
        __hip_atomic_store(&h_tag[(size_t)(u0+gul)*32 + gb], 0ull,
                           __ATOMIC_RELAXED, __HIP_MEMORY_SCOPE_AGENT);
    for (int i = tid; i < 1024; i += 576) {
        int row2 = i & 31, n = i >> 5;
        xbuf[row2*33 + n] = Xenc[(size_t)((n>>3)*512 + u0 + (n&7))*32 + row2];
    }
    __syncthreads();

    float c_reg = 0.f;
    float xr[16];

    #define MM6(ACC, AH0, AH1, AL0, AL1, WH0, WH1, WL0, WL1) do { \
        ACC = __builtin_amdgcn_mfma_f32_16x16x32_bf16(AH0, WH0, ACC, 0,0,0); \
        ACC = __builtin_amdgcn_mfma_f32_16x16x32_bf16(AH1, WH1, ACC, 0,0,0); \
        ACC = __builtin_amdgcn_mfma_f32_16x16x32_bf16(AL0, WH0, ACC, 0,0,0); \
        ACC = __builtin_amdgcn_mfma_f32_16x16x32_bf16(AL1, WH1, ACC, 0,0,0); \
        ACC = __builtin_amdgcn_mfma_f32_16x16x32_bf16(AH0, WL0, ACC, 0,0,0); \
        ACC = __builtin_amdgcn_mfma_f32_16x16x32_bf16(AH1, WL1, ACC, 0,0,0); \
    } while(0)

    for (int g = 0; g < NT_STEPS; ++g) {
        const bool enc = g < TT;

        if (w < 8) {
            // ---- poll own operand words until tag==g (detect+data fused) ----
            const unsigned long long* hb = h_tag + (size_t)(g % 3)*16384;
            const unsigned int etag = (unsigned int)g;
            unsigned long long va[4][8];
            bool ok = false;
            while (!ok) {
                #pragma unroll
                for (int grp = 0; grp < 4; ++grp) {
                    const int kbase = w*64 + (grp & 1)*32 + kg;
                    const int brow  = (grp >> 1)*16 + rl;
                    #pragma unroll
                    for (int j = 0; j < 8; ++j)
                        va[grp][j] = __hip_atomic_load(&hb[(size_t)(kbase+j)*32 + brow],
                                        __ATOMIC_RELAXED, __HIP_MEMORY_SCOPE_AGENT);
                }
                ok = true;
                #pragma unroll
                for (int grp = 0; grp < 4; ++grp) {
                    #pragma unroll
                    for (int j = 0; j < 8; ++j)
                        ok = ok & ((unsigned int)(va[grp][j] >> 32) == etag);
                }
            }
            short8v aH[4], aL[4];
            #pragma unroll
            for (int grp = 0; grp < 4; ++grp) {
                #pragma unroll
                for (int j = 0; j < 8; ++j) {
                    unsigned int lo = (unsigned int)va[grp][j];
                    aH[grp][j] = (short)(lo & 0xffffu);
                    aL[grp][j] = (short)(lo >> 16);
                }
            }
            f32x4 acc00={0,0,0,0}, acc01={0,0,0,0}, acc10={0,0,0,0}, acc11={0,0,0,0};
            if (enc) {
                MM6(acc00, aH[0],aH[1],aL[0],aL[1], eH00,eH01,eL00,eL01);
                MM6(acc01, aH[0],aH[1],aL[0],aL[1], eH10,eH11,eL10,eL11);
                MM6(acc10, aH[2],aH[3],aL[2],aL[3], eH00,eH01,eL00,eL01);
                MM6(acc11, aH[2],aH[3],aL[2],aL[3], eH10,eH11,eL10,eL11);
            } else {
                MM6(acc00, aH[0],aH[1],aL[0],aL[1], dH00,dH01,dL00,dL01);
                MM6(acc01, aH[0],aH[1],aL[0],aL[1], dH10,dH11,dL10,dL11);
                MM6(acc10, aH[2],aH[3],aL[2],aL[3], dH00,dH01,dL00,dL01);
                MM6(acc11, aH[2],aH[3],aL[2],aL[3], dH10,dH11,dL10,dL11);
            }
            #pragma unroll
            for (int j = 0; j < 4; ++j) {
                partials[(w*32 +      r4 + j)*36 +      rl] = acc00[j];
                partials[(w*32 +      r4 + j)*36 + 16 + rl] = acc01[j];
                partials[(w*32 + 16 + r4 + j)*36 +      rl] = acc10[j];
                partials[(w*32 + 16 + r4 + j)*36 + 16 + rl] = acc11[j];
            }
        } else {
            // ---- staging wave: issue X(g+1) HBM loads (own vmcnt) ----
            if (g + 1 < NT_STEPS) {
                const int tn = (g+1 < TT) ? g+1 : g+1-TT;
                const float* Xt = ((g+1 < TT) ? Xenc : Xdec) + (size_t)tn*G4*BB;
                #pragma unroll
                for (int q = 0; q < 16; ++q) {
                    int i = q*64 + l;
                    int row2 = i & 31, n = i >> 5;
                    xr[q] = Xt[(size_t)((n>>3)*512 + u0 + (n&7))*32 + row2];
                }
            }
        }

        // BARRIER A (raw: LDS drain only, no vmcnt)
        asm volatile("s_waitcnt lgkmcnt(0)" ::: "memory");
        __builtin_amdgcn_s_barrier();

        if (tid < 256) {
            float pre[4];
            #pragma unroll
            for (int gg = 0; gg < 4; ++gg) {
                float s = xbuf[(g & 1)*1056 + gb*33 + gg*8 + gul];
                #pragma unroll
                for (int ww = 0; ww < 8; ++ww)
                    s += partials[(ww*32 + gb)*36 + gg*8 + gul];
                pre[gg] = s;
            }
            float iv = 1.f/(1.f + expf(-pre[0]));
            float fv = 1.f/(1.f + expf(-pre[1]));
            float gv = tanhf(pre[2]);
            float ov = 1.f/(1.f + expf(-pre[3]));
            c_reg = fmaf(fv, c_reg, iv*gv);
            float hv = ov * tanhf(c_reg);
            unsigned short hh = bf16_rne(hv);
            unsigned short hl = bf16_rne(hv - bf16f(hh));
            unsigned long long word =
                ((unsigned long long)(unsigned int)(g + 1) << 32)
              | (unsigned long long)((unsigned int)hh | ((unsigned int)hl << 16));
            __hip_atomic_store(&h_tag[(size_t)((g+1)%3)*16384 + (size_t)(u0+gul)*32 + gb],
                               word, __ATOMIC_RELAXED, __HIP_MEMORY_SCOPE_AGENT);
            if (!enc) hs[((size_t)(g-TT)*BB + gb)*HID + u0 + gul] = hv;
        } else if (w == 8 && g + 1 < NT_STEPS) {
            #pragma unroll
            for (int q = 0; q < 16; ++q) {
                int i = q*64 + l;
                int row2 = i & 31, n = i >> 5;
                xbuf[((g+1) & 1)*1056 + row2*33 + n] = xr[q];
            }
        }

        // BARRIER B (raw)
        asm volatile("s_waitcnt lgkmcnt(0)" ::: "memory");
        __builtin_amdgcn_s_barrier();
    }
}

// ---------------- transpose fc_W (512 x 10000) -> (10000 x 512) ----------------
__global__ void transpose_fc(const float* __restrict__ W, float* __restrict__ Wt)
{
    __shared__ float tile[32][33];
    int v0 = blockIdx.x*32, k0 = blockIdx.y*32;
    int tx = threadIdx.x, ty = threadIdx.y;  // (32,8)
    #pragma unroll
    for (int r = 0; r < 32; r += 8) {
        int k = k0 + ty + r, v = v0 + tx;
        tile[ty+r][tx] = (v < NV) ? W[(size_t)k*NV + v] : 0.f;
    }
    __syncthreads();
    #pragma unroll
    for (int r = 0; r < 32; r += 8) {
        int v = v0 + ty + r, k = k0 + tx;
        if (v < NV) Wt[(size_t)v*HID + k] = tile[tx][ty+r];
    }
}

// ---------------- norms for rigorous logit bound ----------------
__global__ void wnorm(const float* __restrict__ W, const float* __restrict__ bvec,
                      unsigned int* __restrict__ scal)
{
    int v = blockIdx.x*256 + threadIdx.x;
    if (v < NV) {
        float s = 0.f;
        for (int k = 0; k < HID; k++) { float w = W[(size_t)k*NV + v]; s = fmaf(w, w, s); }
        atomicMax(&scal[0], __float_as_uint(s));
        atomicMax(&scal[1], __float_as_uint(fabsf(bvec[v])));
    }
}

__global__ void hnorm(const float* __restrict__ hs, unsigned int* __restrict__ scal)
{
    int r = blockIdx.x, lane = threadIdx.x;  // 64 threads
    float s = 0.f;
    for (int k = lane; k < HID; k += 64) { float x = hs[(size_t)r*HID + k]; s = fmaf(x, x, s); }
    for (int o = 32; o; o >>= 1) s += __shfl_down(s, o);
    if (lane == 0) atomicMax(&scal[2], __float_as_uint(s));
}

// ---------------- routing ----------------
__global__ void routing(const int* __restrict__ ids, const int* __restrict__ mask,
                        int* __restrict__ exclk, int* __restrict__ winner)
{
    int b = blockIdx.x;
    __shared__ int pre[TT];
    int t = threadIdx.x;
    if (t == 0) { int s = 0; for (int i = 0; i < TT; i++) { pre[i] = s; s += mask[b*TT+i]; } }
    __syncthreads();
    exclk[b*TT + t] = pre[t];
    if (mask[b*TT + t] == 0) winner[b*TT + t] = ids[b*TT + t];
}

// ---------------- per-row gumbel max ----------------
__global__ __launch_bounds__(256) void rowmax(const int* __restrict__ mask,
        const int* __restrict__ exclk, const float* __restrict__ gum, float* __restrict__ Mr)
{
    int row = blockIdx.x, b = row >> 7, t = row & 127;
    if (t == 0 || mask[row] == 0) return;
    int k = exclk[row];
    const float* g = gum + ((size_t)k*BB + b)*NV;
    float m = -1e30f;
    for (int v = threadIdx.x; v < NV; v += 256) m = fmaxf(m, g[v]);
    __shared__ float red[256];
    red[threadIdx.x] = m; __syncthreads();
    for (int s = 128; s; s >>= 1) {
        if (threadIdx.x < s) red[threadIdx.x] = fmaxf(red[threadIdx.x], red[threadIdx.x+s]);
        __syncthreads();
    }
    if (threadIdx.x == 0) Mr[row] = red[0];
}

// ---------------- candidate scan + exact fp32 logits + argmax ----------------
__global__ __launch_bounds__(256) void cand_argmax(const int* __restrict__ mask,
        const int* __restrict__ exclk, const float* __restrict__ gum,
        const float* __restrict__ rinit, const float* __restrict__ hs,
        const float* __restrict__ Wt, const float* __restrict__ fcb,
        const float* __restrict__ Mr, const unsigned int* __restrict__ scal,
        int* __restrict__ winner)
{
    int row = blockIdx.x, b = row >> 7, t = row & 127;
    if (mask[row] == 0) return;
    int tid = threadIdx.x;
    __shared__ float red[256];
    __shared__ int idxr[256];
    __shared__ int list[256];
    __shared__ int wcnt[4];

    if (t == 0) {
        const float* g  = gum   + (size_t)b*NV;
        const float* r0 = rinit + (size_t)b*NV;
        float bs = -1e30f; int bv = 0x7fffffff;
        for (int v = tid; v < NV; v += 256) {
            float sc = r0[v] + g[v];
            if (sc > bs) { bs = sc; bv = v; }
        }
        red[tid] = bs; idxr[tid] = bv; __syncthreads();
        for (int s = 128; s; s >>= 1) {
            if (tid < s) {
                if (red[tid+s] > red[tid] || (red[tid+s] == red[tid] && idxr[tid+s] < idxr[tid])) {
                    red[tid] = red[tid+s]; idxr[tid] = idxr[tid+s];
                }
            }
            __syncthreads();
        }
        if (tid == 0) winner[row] = idxr[0];
        return;
    }

    int k = exclk[row];
    const float* g    = gum + ((size_t)k*BB + b)*NV;
    const float* hrow = hs + ((size_t)(t-1)*BB + b)*HID;
    float bound = sqrtf(__uint_as_float(scal[0])) * sqrtf(__uint_as_float(scal[2]))
                + __uint_as_float(scal[1]);
    float thr = Mr[row] - 2.0f*bound*1.05f - 1e-6f;

    float curS = -1e30f; int curV = 0x7fffffff;
    int wv = tid >> 6, lane = tid & 63;
    for (int v0 = 0; v0 < NV; v0 += 256) {
        int v = v0 + tid;
        bool ok = (v < NV) && (g[v] >= thr);
        unsigned long long mb = __ballot(ok);
        if (lane == 0) wcnt[wv] = __popcll(mb);
        __syncthreads();
        int off = 0;
        #pragma unroll
        for (int w = 0; w < 4; w++) if (w < wv) off += wcnt[w];
        int tot = wcnt[0] + wcnt[1] + wcnt[2] + wcnt[3];
        if (ok) {
            int pos = off + __popcll(mb & ((1ull << lane) - 1ull));
            list[pos] = v;
        }
        __syncthreads();
        for (int ci = 0; ci < tot; ci++) {
            int vc = list[ci];
            float p = 0.f;
            for (int k2 = tid; k2 < HID; k2 += 256)
                p = fmaf(hrow[k2], Wt[(size_t)vc*HID + k2], p);
            red[tid] = p; __syncthreads();
            for (int s = 128; s; s >>= 1) {
                if (tid < s) red[tid] += red[tid+s];
                __syncthreads();
            }
            if (tid == 0) {
                float sc = (red[0] + fcb[vc]) + g[vc];
                if (sc > curS || (sc == curS && vc < curV)) { curS = sc; curV = vc; }
            }
            __syncthreads();
        }
    }
    if (tid == 0) winner[row] = curV;
}

// ---------------- write one-hot output ----------------
__global__ __launch_bounds__(256) void write_out(const int* __restrict__ winner,
                                                 float* __restrict__ out)
{
    int row = blockIdx.x;
    int win = winner[row];
    float4* o = (float4*)(out + (size_t)row*NV);
    int tid = threadIdx.x;
    #pragma unroll
    for (int i = 0; i < 10; i++) {
        int idx = tid + i*256;
        if (idx < 2500) {
            int vb = idx*4;
            float4 val = {0.f, 0.f, 0.f, 0.f};
            if (win >= vb && win < vb+4) ((float*)&val)[win - vb] = 1.0f;
            o[idx] = val;
        }
    }
}

extern "C" void kernel_launch(void* const* d_in, const int* in_sizes, int n_in,
                              void* d_out, int out_size, void* d_ws, size_t ws_size,
                              hipStream_t stream)
{
    const int*   ids   = (const int*)d_in[0];
    const int*   mask  = (const int*)d_in[1];
    const float* eEmb  = (const float*)d_in[2];
    const float* eWih  = (const float*)d_in[3];
    const float* eWhh  = (const float*)d_in[4];
    const float* eB    = (const float*)d_in[5];
    const float* dEmb  = (const float*)d_in[6];
    const float* dWih  = (const float*)d_in[7];
    const float* dWhh  = (const float*)d_in[8];
    const float* dB    = (const float*)d_in[9];
    const float* fcW   = (const float*)d_in[10];
    const float* fcb   = (const float*)d_in[11];
    const float* rinit = (const float*)d_in[12];
    const float* gum   = (const float*)d_in[13];
    float* out = (float*)d_out;

    unsigned long long* h_tag = (unsigned long long*)d_ws;   // [3][512][32] u64
    float* wsf = (float*)(h_tag + 3*16384);
    size_t off = 0;
    float* Xenc = wsf + off; off += (size_t)TT*BB*G4;        // [t][col][b]
    float* Xdec = wsf + off; off += (size_t)TD*BB*G4;
    float* hs   = wsf + off; off += (size_t)TD*BB*HID;
    float* fcWt = wsf + off; off += (size_t)NV*HID;
    float* Mr   = wsf + off; off += 4096;
    unsigned int* scal = (unsigned int*)(wsf + off); off += 8;
    int* exclk  = (int*)(wsf + off); off += 4096;
    int* winner = (int*)(wsf + off); off += 4096;

    // invalidate all tags each launch (0xFFFFFFFF != any step tag)
    hipMemsetAsync(h_tag, 0xFF, (size_t)3*16384*sizeof(unsigned long long), stream);
    hipMemsetAsync(scal,  0, 8*sizeof(int), stream);

    dim3 gblk(16, 32);
    gemm_x<<<gblk, 256, 0, stream>>>(ids, eEmb, eWih, eB, Xenc, TT*BB);
    gemm_x<<<gblk, 256, 0, stream>>>(ids, dEmb, dWih, dB, Xdec, TD*BB);
    transpose_fc<<<dim3(313,16), dim3(32,8), 0, stream>>>(fcW, fcWt);
    wnorm<<<40, 256, 0, stream>>>(fcW, fcb, scal);
    routing<<<32, 128, 0, stream>>>(ids, mask, exclk, winner);

    lstm_persist<<<NB, 576, 0, stream>>>(Xenc, Xdec, eWhh, dWhh, h_tag, hs);

    hnorm<<<TD*BB, 64, 0, stream>>>(hs, scal);
    rowmax<<<4096, 256, 0, stream>>>(mask, exclk, gum, Mr);
    cand_argmax<<<4096, 256, 0, stream>>>(mask, exclk, gum, rinit, hs, fcWt, fcb, Mr, scal, winner);
    write_out<<<4096, 256, 0, stream>>>(winner, out);
}

// Round 7
// 1459.758 us; speedup vs baseline: 1.6487x; 1.6487x over previous
//
#include <hip/hip_runtime.h>
#include <hip/hip_bf16.h>
#include <math.h>

#define BB 32
#define TT 128
#define TD 127
#define EMB 256
#define HID 512
#define G4 2048
#define NV 10000
#define NB 64
#define UPB 8      // units per block -> 32 gate cols
#define NT_STEPS (TT + TD)

typedef __attribute__((ext_vector_type(8))) short short8v;
typedef __attribute__((ext_vector_type(4))) float f32x4;

__device__ __forceinline__ unsigned short bf16_rne(float x){
    unsigned int u = __float_as_uint(x);
    u += 0x7fffu + ((u >> 16) & 1u);
    return (unsigned short)(u >> 16);
}
__device__ __forceinline__ float bf16f(unsigned short h){
    return __uint_as_float(((unsigned int)h) << 16);
}

// ---------------- GEMM: X[t][col][b] = embed[tok] @ W + bias ----------------
__global__ __launch_bounds__(256) void gemm_x(const int* __restrict__ ids,
        const float* __restrict__ embed, const float* __restrict__ W,
        const float* __restrict__ bias, float* __restrict__ X, int M)
{
    __shared__ float As[16][128];
    __shared__ float Bs[16][128];
    __shared__ int toks[128];
    const int tid = threadIdx.x;
    const int m0 = blockIdx.y * 128, n0 = blockIdx.x * 128;
    if (tid < 128) {
        int mr = m0 + tid, tk = 0;
        if (mr < M) { int t = mr >> 5, b = mr & 31; tk = ids[b*TT + t]; }
        toks[tid] = tk;
    }
    __syncthreads();
    float acc[8][8] = {};
    const int ty = tid >> 4, tx = tid & 15;
    for (int kt = 0; kt < EMB; kt += 16) {
        #pragma unroll
        for (int i = 0; i < 2; i++) {
            int idx = tid*2 + i;
            int row = idx >> 2, k4 = (idx & 3)*4;
            float4 a = *(const float4*)&embed[(size_t)toks[row]*EMB + kt + k4];
            As[k4+0][row] = a.x; As[k4+1][row] = a.y; As[k4+2][row] = a.z; As[k4+3][row] = a.w;
        }
        #pragma unroll
        for (int i = 0; i < 2; i++) {
            int idx = tid*2 + i;
            int kr = idx >> 5, c4 = (idx & 31)*4;
            *(float4*)&Bs[kr][c4] = *(const float4*)&W[(size_t)(kt+kr)*G4 + n0 + c4];
        }
        __syncthreads();
        #pragma unroll
        for (int k = 0; k < 16; k++) {
            float a8[8], b8[8];
            #pragma unroll
            for (int i = 0; i < 8; i++) a8[i] = As[k][ty*8+i];
            #pragma unroll
            for (int j = 0; j < 8; j++) b8[j] = Bs[k][tx*8+j];
            #pragma unroll
            for (int i = 0; i < 8; i++) {
                #pragma unroll
                for (int j = 0; j < 8; j++)
                    acc[i][j] = fmaf(a8[i], b8[j], acc[i][j]);
            }
        }
        __syncthreads();
    }
    #pragma unroll
    for (int i = 0; i < 8; i++) {
        int mr = m0 + ty*8 + i;
        if (mr < M) {
            int tt = mr >> 5, bb2 = mr & 31;
            #pragma unroll
            for (int j = 0; j < 8; j++) {
                int nc = n0 + tx*8 + j;
                X[((size_t)tt*G4 + nc)*BB + bb2] = acc[i][j] + bias[nc];
            }
        }
    }
}

// ---------------- Persistent MFMA LSTM (round-5 core + per-wave flags) -----
// 64 blocks x 512 thr (8 waves). Block owns 8 units -> 32 gate cols.
// Wave w: K-slice [64w,64w+64) -> producer blocks 8w..8w+7.
// Sync fabric: per-wave sub-flags subflags[bid*4+wv] stored after that gate
// wave's own vmcnt(0) drain (per-wave counter) -- no block barrier between
// h store and flag. Consumers poll ONLY their 32 sub-flags (one cache line
// region) at loop top, then load h once. Union of the 8 waves' polls covers
// all 64 blocks before the post-MFMA barrier, preserving the 2-deep
// ping-pong safety induction. 2 raw lgkm-only barriers per step.
__global__ __launch_bounds__(512) void lstm_persist(
        const float* __restrict__ Xenc, const float* __restrict__ Xdec,
        const float* __restrict__ Whh_e, const float* __restrict__ Whh_d,
        unsigned int* __restrict__ h_pk,   // [2][512][32] (bf16hi | bf16lo<<16)
        float* __restrict__ hs,            // [127][32][512]
        int* __restrict__ subflags)        // [64*4]
{
    __shared__ float smem[11328];
    float* partials = smem;            // [8][32][36] (also W-stage scratch)
    float* xbuf     = smem + 9216;     // [2][32][33]

    const int tid = threadIdx.x;
    const int bid = blockIdx.x;
    const int u0  = bid*UPB;
    const int w   = tid >> 6;
    const int l   = tid & 63;
    const int rl  = l & 15;            // A-row / B-col / C-col in tile
    const int kg  = (l >> 4) * 8;      // frag k sub-base
    const int r4  = (l >> 4) * 4;      // C row base
    const int gb  = tid >> 3, gul = tid & 7;   // gate mapping (tid<256)

    short8v eH00,eH01,eH10,eH11, eL00,eL01,eL10,eL11;   // enc W frags
    short8v dH00,dH01,dH10,dH11, dL00,dL01,dL10,dL11;   // dec W frags

    #define BW(WH, WL, KB, CO) do { _Pragma("unroll") \
        for (int j = 0; j < 8; ++j) { \
            float wv2 = partials[((KB)+j)*32 + (CO) + rl]; \
            unsigned short htop = bf16_rne(wv2); \
            WH[j] = (short)htop; \
            WL[j] = (short)bf16_rne(wv2 - bf16f(htop)); \
        } } while(0)

    #define STAGEB(SRC, H00,H01,H10,H11, L00,L01,L10,L11) do { \
        for (int c = 0; c < 4; ++c) { \
            __syncthreads(); \
            for (int i = tid; i < 4096; i += 512) { \
                int kl = i >> 5, n = i & 31; \
                partials[kl*32 + n] = SRC[(size_t)(c*128 + kl)*G4 + (size_t)((n>>3)*512 + u0 + (n&7))]; \
            } \
            __syncthreads(); \
            if ((w >> 1) == c) { \
                int kb0 = 64*(w & 1) + kg; \
                BW(H00, L00, kb0,      0); \
                BW(H01, L01, kb0 + 32, 0); \
                BW(H10, L10, kb0,     16); \
                BW(H11, L11, kb0 + 32,16); \
            } \
        } } while(0)

    STAGEB(Whh_e, eH00,eH01,eH10,eH11, eL00,eL01,eL10,eL11);
    STAGEB(Whh_d, dH00,dH01,dH10,dH11, dL00,dL01,dL10,dL11);

    // prologue: stage X(0) into xbuf[0]
    __syncthreads();
    for (int i = tid; i < 1024; i += 512) {
        int row2 = i & 31, n = i >> 5;
        xbuf[row2*33 + n] = Xenc[(size_t)((n>>3)*512 + u0 + (n&7))*32 + row2];
    }
    __syncthreads();

    float c_reg = 0.f;

    #define MM6(ACC, AH0, AH1, AL0, AL1, WH0, WH1, WL0, WL1) do { \
        ACC = __builtin_amdgcn_mfma_f32_16x16x32_bf16(AH0, WH0, ACC, 0,0,0); \
        ACC = __builtin_amdgcn_mfma_f32_16x16x32_bf16(AH1, WH1, ACC, 0,0,0); \
        ACC = __builtin_amdgcn_mfma_f32_16x16x32_bf16(AL0, WH0, ACC, 0,0,0); \
        ACC = __builtin_amdgcn_mfma_f32_16x16x32_bf16(AL1, WH1, ACC, 0,0,0); \
        ACC = __builtin_amdgcn_mfma_f32_16x16x32_bf16(AH0, WL0, ACC, 0,0,0); \
        ACC = __builtin_amdgcn_mfma_f32_16x16x32_bf16(AH1, WL1, ACC, 0,0,0); \
    } while(0)

    for (int g = 0; g < NT_STEPS; ++g) {
        const bool enc = g < TT;

        f32x4 acc00={0,0,0,0}, acc01={0,0,0,0}, acc10={0,0,0,0}, acc11={0,0,0,0};
        if (g > 0) {
            // ---- per-wave poll: 32 sub-flags of this wave's 8 producers ----
            {
                const bool act = l < 32;
                const int sidx = (w*8 + (l >> 2))*4 + (l & 3);
                while (true) {
                    int f = act ? __hip_atomic_load(&subflags[sidx],
                                __ATOMIC_RELAXED, __HIP_MEMORY_SCOPE_AGENT)
                                : 0x7fffffff;
                    if (__ballot((!act) || (f >= g)) == ~0ull) break;
                }
                __builtin_amdgcn_sched_barrier(0);
                asm volatile("" ::: "memory");
            }
            const unsigned int* hp = h_pk + (size_t)(g & 1)*16384;
            short8v aH_m0k0, aH_m0k1, aH_m1k0, aH_m1k1;
            short8v aL_m0k0, aL_m0k1, aL_m1k0, aL_m1k1;
            #define LOAD_A(AH, AL, MT, KS) do { \
                unsigned int pv[8]; \
                int kbase = w*64 + (KS)*32 + kg; \
                int brow = (MT)*16 + rl; \
                _Pragma("unroll") \
                for (int j = 0; j < 8; ++j) \
                    pv[j] = __hip_atomic_load(&hp[(kbase+j)*32 + brow], \
                                __ATOMIC_RELAXED, __HIP_MEMORY_SCOPE_AGENT); \
                _Pragma("unroll") \
                for (int j = 0; j < 8; ++j) { \
                    AH[j] = (short)(pv[j] & 0xffffu); \
                    AL[j] = (short)(pv[j] >> 16); \
                } } while(0)
            LOAD_A(aH_m0k0, aL_m0k0, 0, 0); LOAD_A(aH_m0k1, aL_m0k1, 0, 1);
            LOAD_A(aH_m1k0, aL_m1k0, 1, 0); LOAD_A(aH_m1k1, aL_m1k1, 1, 1);
            if (enc) {
                MM6(acc00, aH_m0k0, aH_m0k1, aL_m0k0, aL_m0k1, eH00,eH01,eL00,eL01);
                MM6(acc01, aH_m0k0, aH_m0k1, aL_m0k0, aL_m0k1, eH10,eH11,eL10,eL11);
                MM6(acc10, aH_m1k0, aH_m1k1, aL_m1k0, aL_m1k1, eH00,eH01,eL00,eL01);
                MM6(acc11, aH_m1k0, aH_m1k1, aL_m1k0, aL_m1k1, eH10,eH11,eL10,eL11);
            } else {
                MM6(acc00, aH_m0k0, aH_m0k1, aL_m0k0, aL_m0k1, dH00,dH01,dL00,dL01);
                MM6(acc01, aH_m0k0, aH_m0k1, aL_m0k0, aL_m0k1, dH10,dH11,dL10,dL11);
                MM6(acc10, aH_m1k0, aH_m1k1, aL_m1k0, aL_m1k1, dH00,dH01,dL00,dL01);
                MM6(acc11, aH_m1k0, aH_m1k1, aL_m1k0, aL_m1k1, dH10,dH11,dL10,dL11);
            }
        }
        #pragma unroll
        for (int j = 0; j < 4; ++j) {
            partials[(w*32 +      r4 + j)*36 +      rl] = acc00[j];
            partials[(w*32 +      r4 + j)*36 + 16 + rl] = acc01[j];
            partials[(w*32 + 16 + r4 + j)*36 +      rl] = acc10[j];
            partials[(w*32 + 16 + r4 + j)*36 + 16 + rl] = acc11[j];
        }
        // BARRIER 1 (raw; partials ready -- block-wide join absorbs skew here)
        asm volatile("s_waitcnt lgkmcnt(0)" ::: "memory");
        __builtin_amdgcn_s_barrier();

        if (tid < 256) {
            float pre[4];
            #pragma unroll
            for (int gg = 0; gg < 4; ++gg) {
                float s = xbuf[(g & 1)*1056 + gb*33 + gg*8 + gul];
                #pragma unroll
                for (int ww = 0; ww < 8; ++ww)
                    s += partials[(ww*32 + gb)*36 + gg*8 + gul];
                pre[gg] = s;
            }
            float iv = 1.f/(1.f + expf(-pre[0]));
            float fv = 1.f/(1.f + expf(-pre[1]));
            float gv = tanhf(pre[2]);
            float ov = 1.f/(1.f + expf(-pre[3]));
            c_reg = fmaf(fv, c_reg, iv*gv);
            float hv = ov * tanhf(c_reg);
            unsigned short hh = bf16_rne(hv);
            unsigned short hl = bf16_rne(hv - bf16f(hh));
            unsigned int pk = (unsigned int)hh | ((unsigned int)hl << 16);
            __hip_atomic_store(&h_pk[(size_t)((g+1) & 1)*16384 + (u0+gul)*32 + gb],
                               pk, __ATOMIC_RELAXED, __HIP_MEMORY_SCOPE_AGENT);
            // per-wave drain of OWN h stores, then this wave's sub-flag
            asm volatile("s_waitcnt vmcnt(0)" ::: "memory");
            if (g < NT_STEPS - 1 && l == 0)
                __hip_atomic_store(&subflags[bid*4 + w], g + 1,
                                   __ATOMIC_RELAXED, __HIP_MEMORY_SCOPE_AGENT);
            // off critical path
            if (!enc) hs[((size_t)(g-TT)*BB + gb)*HID + u0 + gul] = hv;
        } else if (g + 1 < NT_STEPS) {
            // waves 4-7: stage X(g+1) into the other xbuf half
            const int tn = (g+1 < TT) ? g+1 : g+1-TT;
            const float* Xt = ((g+1 < TT) ? Xenc : Xdec) + (size_t)tn*G4*BB;
            #pragma unroll
            for (int j = 0; j < 4; ++j) {
                int i = (tid - 256) + j*256;
                int row2 = i & 31, n = i >> 5;
                xbuf[((g+1) & 1)*1056 + row2*33 + n] =
                    Xt[(size_t)((n>>3)*512 + u0 + (n&7))*32 + row2];
            }
        }
        // BARRIER 2 (raw; xbuf writes done, partials reads done)
        asm volatile("s_waitcnt lgkmcnt(0)" ::: "memory");
        __builtin_amdgcn_s_barrier();
    }
}

// ---------------- transpose fc_W (512 x 10000) -> (10000 x 512) ----------------
__global__ void transpose_fc(const float* __restrict__ W, float* __restrict__ Wt)
{
    __shared__ float tile[32][33];
    int v0 = blockIdx.x*32, k0 = blockIdx.y*32;
    int tx = threadIdx.x, ty = threadIdx.y;  // (32,8)
    #pragma unroll
    for (int r = 0; r < 32; r += 8) {
        int k = k0 + ty + r, v = v0 + tx;
        tile[ty+r][tx] = (v < NV) ? W[(size_t)k*NV + v] : 0.f;
    }
    __syncthreads();
    #pragma unroll
    for (int r = 0; r < 32; r += 8) {
        int v = v0 + ty + r, k = k0 + tx;
        if (v < NV) Wt[(size_t)v*HID + k] = tile[tx][ty+r];
    }
}

// ---------------- norms for rigorous logit bound ----------------
__global__ void wnorm(const float* __restrict__ W, const float* __restrict__ bvec,
                      unsigned int* __restrict__ scal)
{
    int v = blockIdx.x*256 + threadIdx.x;
    if (v < NV) {
        float s = 0.f;
        for (int k = 0; k < HID; k++) { float w = W[(size_t)k*NV + v]; s = fmaf(w, w, s); }
        atomicMax(&scal[0], __float_as_uint(s));
        atomicMax(&scal[1], __float_as_uint(fabsf(bvec[v])));
    }
}

__global__ void hnorm(const float* __restrict__ hs, unsigned int* __restrict__ scal)
{
    int r = blockIdx.x, lane = threadIdx.x;  // 64 threads
    float s = 0.f;
    for (int k = lane; k < HID; k += 64) { float x = hs[(size_t)r*HID + k]; s = fmaf(x, x, s); }
    for (int o = 32; o; o >>= 1) s += __shfl_down(s, o);
    if (lane == 0) atomicMax(&scal[2], __float_as_uint(s));
}

// ---------------- routing ----------------
__global__ void routing(const int* __restrict__ ids, const int* __restrict__ mask,
                        int* __restrict__ exclk, int* __restrict__ winner)
{
    int b = blockIdx.x;
    __shared__ int pre[TT];
    int t = threadIdx.x;
    if (t == 0) { int s = 0; for (int i = 0; i < TT; i++) { pre[i] = s; s += mask[b*TT+i]; } }
    __syncthreads();
    exclk[b*TT + t] = pre[t];
    if (mask[b*TT + t] == 0) winner[b*TT + t] = ids[b*TT + t];
}

// ---------------- per-row gumbel max ----------------
__global__ __launch_bounds__(256) void rowmax(const int* __restrict__ mask,
        const int* __restrict__ exclk, const float* __restrict__ gum, float* __restrict__ Mr)
{
    int row = blockIdx.x, b = row >> 7, t = row & 127;
    if (t == 0 || mask[row] == 0) return;
    int k = exclk[row];
    const float* g = gum + ((size_t)k*BB + b)*NV;
    float m = -1e30f;
    for (int v = threadIdx.x; v < NV; v += 256) m = fmaxf(m, g[v]);
    __shared__ float red[256];
    red[threadIdx.x] = m; __syncthreads();
    for (int s = 128; s; s >>= 1) {
        if (threadIdx.x < s) red[threadIdx.x] = fmaxf(red[threadIdx.x], red[threadIdx.x+s]);
        __syncthreads();
    }
    if (threadIdx.x == 0) Mr[row] = red[0];
}

// ---------------- candidate scan + exact fp32 logits + argmax ----------------
__global__ __launch_bounds__(256) void cand_argmax(const int* __restrict__ mask,
        const int* __restrict__ exclk, const float* __restrict__ gum,
        const float* __restrict__ rinit, const float* __restrict__ hs,
        const float* __restrict__ Wt, const float* __restrict__ fcb,
        const float* __restrict__ Mr, const unsigned int* __restrict__ scal,
        int* __restrict__ winner)
{
    int row = blockIdx.x, b = row >> 7, t = row & 127;
    if (mask[row] == 0) return;
    int tid = threadIdx.x;
    __shared__ float red[256];
    __shared__ int idxr[256];
    __shared__ int list[256];
    __shared__ int wcnt[4];

    if (t == 0) {
        const float* g  = gum   + (size_t)b*NV;
        const float* r0 = rinit + (size_t)b*NV;
        float bs = -1e30f; int bv = 0x7fffffff;
        for (int v = tid; v < NV; v += 256) {
            float sc = r0[v] + g[v];
            if (sc > bs) { bs = sc; bv = v; }
        }
        red[tid] = bs; idxr[tid] = bv; __syncthreads();
        for (int s = 128; s; s >>= 1) {
            if (tid < s) {
                if (red[tid+s] > red[tid] || (red[tid+s] == red[tid] && idxr[tid+s] < idxr[tid])) {
                    red[tid] = red[tid+s]; idxr[tid] = idxr[tid+s];
                }
            }
            __syncthreads();
        }
        if (tid == 0) winner[row] = idxr[0];
        return;
    }

    int k = exclk[row];
    const float* g    = gum + ((size_t)k*BB + b)*NV;
    const float* hrow = hs + ((size_t)(t-1)*BB + b)*HID;
    float bound = sqrtf(__uint_as_float(scal[0])) * sqrtf(__uint_as_float(scal[2]))
                + __uint_as_float(scal[1]);
    float thr = Mr[row] - 2.0f*bound*1.05f - 1e-6f;

    float curS = -1e30f; int curV = 0x7fffffff;
    int wv = tid >> 6, lane = tid & 63;
    for (int v0 = 0; v0 < NV; v0 += 256) {
        int v = v0 + tid;
        bool ok = (v < NV) && (g[v] >= thr);
        unsigned long long mb = __ballot(ok);
        if (lane == 0) wcnt[wv] = __popcll(mb);
        __syncthreads();
        int off = 0;
        #pragma unroll
        for (int w = 0; w < 4; w++) if (w < wv) off += wcnt[w];
        int tot = wcnt[0] + wcnt[1] + wcnt[2] + wcnt[3];
        if (ok) {
            int pos = off + __popcll(mb & ((1ull << lane) - 1ull));
            list[pos] = v;
        }
        __syncthreads();
        for (int ci = 0; ci < tot; ci++) {
            int vc = list[ci];
            float p = 0.f;
            for (int k2 = tid; k2 < HID; k2 += 256)
                p = fmaf(hrow[k2], Wt[(size_t)vc*HID + k2], p);
            red[tid] = p; __syncthreads();
            for (int s = 128; s; s >>= 1) {
                if (tid < s) red[tid] += red[tid+s];
                __syncthreads();
            }
            if (tid == 0) {
                float sc = (red[0] + fcb[vc]) + g[vc];
                if (sc > curS || (sc == curS && vc < curV)) { curS = sc; curV = vc; }
            }
            __syncthreads();
        }
    }
    if (tid == 0) winner[row] = curV;
}

// ---------------- write one-hot output ----------------
__global__ __launch_bounds__(256) void write_out(const int* __restrict__ winner,
                                                 float* __restrict__ out)
{
    int row = blockIdx.x;
    int win = winner[row];
    float4* o = (float4*)(out + (size_t)row*NV);
    int tid = threadIdx.x;
    #pragma unroll
    for (int i = 0; i < 10; i++) {
        int idx = tid + i*256;
        if (idx < 2500) {
            int vb = idx*4;
            float4 val = {0.f, 0.f, 0.f, 0.f};
            if (win >= vb && win < vb+4) ((float*)&val)[win - vb] = 1.0f;
            o[idx] = val;
        }
    }
}

extern "C" void kernel_launch(void* const* d_in, const int* in_sizes, int n_in,
                              void* d_out, int out_size, void* d_ws, size_t ws_size,
                              hipStream_t stream)
{
    const int*   ids   = (const int*)d_in[0];
    const int*   mask  = (const int*)d_in[1];
    const float* eEmb  = (const float*)d_in[2];
    const float* eWih  = (const float*)d_in[3];
    const float* eWhh  = (const float*)d_in[4];
    const float* eB    = (const float*)d_in[5];
    const float* dEmb  = (const float*)d_in[6];
    const float* dWih  = (const float*)d_in[7];
    const float* dWhh  = (const float*)d_in[8];
    const float* dB    = (const float*)d_in[9];
    const float* fcW   = (const float*)d_in[10];
    const float* fcb   = (const float*)d_in[11];
    const float* rinit = (const float*)d_in[12];
    const float* gum   = (const float*)d_in[13];
    float* out = (float*)d_out;

    float* wsf = (float*)d_ws;
    size_t off = 0;
    float* Xenc = wsf + off; off += (size_t)TT*BB*G4;        // [t][col][b]
    float* Xdec = wsf + off; off += (size_t)TD*BB*G4;
    unsigned int* h_pk = (unsigned int*)(wsf + off); off += 2*(size_t)BB*HID;
    float* hs   = wsf + off; off += (size_t)TD*BB*HID;
    float* fcWt = wsf + off; off += (size_t)NV*HID;
    float* Mr   = wsf + off; off += 4096;
    unsigned int* scal = (unsigned int*)(wsf + off); off += 8;
    int* subflags = (int*)(wsf + off); off += NB*4;
    int* exclk  = (int*)(wsf + off); off += 4096;
    int* winner = (int*)(wsf + off); off += 4096;

    hipMemsetAsync(scal,  0, 8*sizeof(int), stream);
    hipMemsetAsync(subflags, 0, NB*4*sizeof(int), stream);

    dim3 gblk(16, 32);
    gemm_x<<<gblk, 256, 0, stream>>>(ids, eEmb, eWih, eB, Xenc, TT*BB);
    gemm_x<<<gblk, 256, 0, stream>>>(ids, dEmb, dWih, dB, Xdec, TD*BB);
    transpose_fc<<<dim3(313,16), dim3(32,8), 0, stream>>>(fcW, fcWt);
    wnorm<<<40, 256, 0, stream>>>(fcW, fcb, scal);
    routing<<<32, 128, 0, stream>>>(ids, mask, exclk, winner);

    lstm_persist<<<NB, 512, 0, stream>>>(Xenc, Xdec, eWhh, dWhh, h_pk, hs, subflags);

    hnorm<<<TD*BB, 64, 0, stream>>>(hs, scal);
    rowmax<<<4096, 256, 0, stream>>>(mask, exclk, gum, Mr);
    cand_argmax<<<4096, 256, 0, stream>>>(mask, exclk, gum, rinit, hs, fcWt, fcb, Mr, scal, winner);
    write_out<<<4096, 256, 0, stream>>>(winner, out);
}

// Round 9
// 1004.449 us; speedup vs baseline: 2.3960x; 1.4533x over previous
//
#include <hip/hip_runtime.h>
#include <hip/hip_bf16.h>
#include <math.h>

#define BB 32
#define TT 128
#define TD 127
#define EMB 256
#define HID 512
#define G4 2048
#define NV 10000
#define NB 64        // lstm blocks
#define NWK 192      // worker blocks
#define GRID_UBER (NB + NWK)
#define UPB 8
#define NT_STEPS (TT + TD)

#define NJOB_DEC 512
#define NJOB_TR  313
#define NJOB_WN  20
#define NJOB_RM  4096
#define NJOBS (NJOB_DEC + NJOB_TR + NJOB_WN + NJOB_RM)

typedef __attribute__((ext_vector_type(8))) short short8v;
typedef __attribute__((ext_vector_type(4))) float f32x4;

__device__ __forceinline__ unsigned short bf16_rne(float x){
    unsigned int u = __float_as_uint(x);
    u += 0x7fffu + ((u >> 16) & 1u);
    return (unsigned short)(u >> 16);
}
__device__ __forceinline__ float bf16f(unsigned short h){
    return __uint_as_float(((unsigned int)h) << 16);
}

// ---------------- GEMM (encoder X): X[t][col][b] = embed[tok] @ W + bias ----
__global__ __launch_bounds__(256) void gemm_x(const int* __restrict__ ids,
        const float* __restrict__ embed, const float* __restrict__ W,
        const float* __restrict__ bias, float* __restrict__ X, int M)
{
    __shared__ float As[16][128];
    __shared__ float Bs[16][128];
    __shared__ int toks[128];
    const int tid = threadIdx.x;
    const int m0 = blockIdx.y * 128, n0 = blockIdx.x * 128;
    if (tid < 128) {
        int mr = m0 + tid, tk = 0;
        if (mr < M) { int t = mr >> 5, b = mr & 31; tk = ids[b*TT + t]; }
        toks[tid] = tk;
    }
    __syncthreads();
    float acc[8][8] = {};
    const int ty = tid >> 4, tx = tid & 15;
    for (int kt = 0; kt < EMB; kt += 16) {
        #pragma unroll
        for (int i = 0; i < 2; i++) {
            int idx = tid*2 + i;
            int row = idx >> 2, k4 = (idx & 3)*4;
            float4 a = *(const float4*)&embed[(size_t)toks[row]*EMB + kt + k4];
            As[k4+0][row] = a.x; As[k4+1][row] = a.y; As[k4+2][row] = a.z; As[k4+3][row] = a.w;
        }
        #pragma unroll
        for (int i = 0; i < 2; i++) {
            int idx = tid*2 + i;
            int kr = idx >> 5, c4 = (idx & 31)*4;
            *(float4*)&Bs[kr][c4] = *(const float4*)&W[(size_t)(kt+kr)*G4 + n0 + c4];
        }
        __syncthreads();
        #pragma unroll
        for (int k = 0; k < 16; k++) {
            float a8[8], b8[8];
            #pragma unroll
            for (int i = 0; i < 8; i++) a8[i] = As[k][ty*8+i];
            #pragma unroll
            for (int j = 0; j < 8; j++) b8[j] = Bs[k][tx*8+j];
            #pragma unroll
            for (int i = 0; i < 8; i++) {
                #pragma unroll
                for (int j = 0; j < 8; j++)
                    acc[i][j] = fmaf(a8[i], b8[j], acc[i][j]);
            }
        }
        __syncthreads();
    }
    #pragma unroll
    for (int i = 0; i < 8; i++) {
        int mr = m0 + ty*8 + i;
        if (mr < M) {
            int tt = mr >> 5, bb2 = mr & 31;
            #pragma unroll
            for (int j = 0; j < 8; j++) {
                int nc = n0 + tx*8 + j;
                X[((size_t)tt*G4 + nc)*BB + bb2] = acc[i][j] + bias[nc];
            }
        }
    }
}

// ---------------- UBER kernel: 64 round-5 LSTM blocks + 192 tail workers ----
__global__ __launch_bounds__(512) void lstm_persist(
        const float* __restrict__ Xenc, float* __restrict__ Xdec,
        const float* __restrict__ Whh_e, const float* __restrict__ Whh_d,
        unsigned int* __restrict__ h_pk,   // [2][512][32]
        float* __restrict__ hs,            // [127][32][512]
        int* __restrict__ flags,           // [64]
        int* __restrict__ decdone,         // [1]
        const int* __restrict__ ids, const float* __restrict__ dEmb,
        const float* __restrict__ dWih, const float* __restrict__ dB,
        const float* __restrict__ fcW, float* __restrict__ fcWt,
        const float* __restrict__ fcb, const int* __restrict__ mask,
        const float* __restrict__ gum, float* __restrict__ Mr,
        unsigned int* __restrict__ scal)
{
    __shared__ float smem[11392];
    const int tid = threadIdx.x;
    const int bid = blockIdx.x;

    if (bid >= NB) {
        // =============== worker blocks: grid-stride job loop ===============
        const int wid = bid - NB;
        for (int job = wid; job < NJOBS; job += NWK) {
            if (job < NJOB_DEC) {
                // ---- decoder-X gemm tile (128m x 128n), 512 threads ----
                const int my = job >> 4, nx = job & 15;
                const int m0 = my*128, n0 = nx*128;
                const int M = TD*BB;
                float* As = smem;              // [16][128]
                float* Bs = smem + 2048;       // [16][128]
                int* toks = (int*)(smem + 4096);
                if (tid < 128) {
                    int mr = m0 + tid, tk = 0;
                    if (mr < M) { int t = mr >> 5, b2 = mr & 31; tk = ids[b2*TT + t]; }
                    toks[tid] = tk;
                }
                __syncthreads();
                float acc[4][8] = {};
                const int ty = tid >> 4, tx = tid & 15;
                for (int kt = 0; kt < EMB; kt += 16) {
                    {
                        int row = tid >> 2, k4 = (tid & 3)*4;
                        float4 a = *(const float4*)&dEmb[(size_t)toks[row]*EMB + kt + k4];
                        As[(k4+0)*128+row] = a.x; As[(k4+1)*128+row] = a.y;
                        As[(k4+2)*128+row] = a.z; As[(k4+3)*128+row] = a.w;
                    }
                    {
                        int kr = tid >> 5, c4 = (tid & 31)*4;
                        *(float4*)&Bs[kr*128 + c4] =
                            *(const float4*)&dWih[(size_t)(kt+kr)*G4 + n0 + c4];
                    }
                    __syncthreads();
                    #pragma unroll
                    for (int k = 0; k < 16; k++) {
                        float a4[4], b8[8];
                        #pragma unroll
                        for (int i = 0; i < 4; i++) a4[i] = As[k*128 + ty*4+i];
                        #pragma unroll
                        for (int j = 0; j < 8; j++) b8[j] = Bs[k*128 + tx*8+j];
                        #pragma unroll
                        for (int i = 0; i < 4; i++) {
                            #pragma unroll
                            for (int j = 0; j < 8; j++)
                                acc[i][j] = fmaf(a4[i], b8[j], acc[i][j]);
                        }
                    }
                    __syncthreads();
                }
                #pragma unroll
                for (int i = 0; i < 4; i++) {
                    int mr = m0 + ty*4 + i;
                    if (mr < M) {
                        int t = mr >> 5, b2 = mr & 31;
                        #pragma unroll
                        for (int j = 0; j < 8; j++) {
                            int nc = n0 + tx*8 + j;
                            Xdec[((size_t)t*G4 + nc)*BB + b2] = acc[i][j] + dB[nc];
                        }
                    }
                }
                __syncthreads();               // all stores acked at L2
                if (tid == 0)                  // release: wbl2 + count
                    __hip_atomic_fetch_add(decdone, 1,
                        __ATOMIC_RELEASE, __HIP_MEMORY_SCOPE_AGENT);
            } else if (job < NJOB_DEC + NJOB_TR) {
                // ---- fc_W transpose strip: 32 v-cols x 512 k ----
                const int v0 = (job - NJOB_DEC)*32;
                float* tile = smem;            // [16][33]
                for (int k0 = 0; k0 < HID; k0 += 16) {
                    {
                        int kk = tid >> 5, vv = tid & 31;
                        int v = v0 + vv;
                        tile[kk*33 + vv] = (v < NV) ? fcW[(size_t)(k0+kk)*NV + v] : 0.f;
                    }
                    __syncthreads();
                    {
                        int vy = tid >> 4, kx = tid & 15;
                        int v = v0 + vy;
                        if (v < NV) fcWt[(size_t)v*HID + k0 + kx] = tile[kx*33 + vy];
                    }
                    __syncthreads();
                }
            } else if (job < NJOB_DEC + NJOB_TR + NJOB_WN) {
                // ---- wnorm: 512 vocab cols ----
                int v = (job - NJOB_DEC - NJOB_TR)*512 + tid;
                if (v < NV) {
                    float s = 0.f;
                    for (int k = 0; k < HID; k++) {
                        float x = fcW[(size_t)k*NV + v]; s = fmaf(x, x, s);
                    }
                    atomicMax(&scal[0], __float_as_uint(s));
                    atomicMax(&scal[1], __float_as_uint(fabsf(fcb[v])));
                }
            } else {
                // ---- rowmax: per-row gumbel max (masked rows, t>=1) ----
                const int row = job - NJOB_DEC - NJOB_TR - NJOB_WN;
                const int b = row >> 7, t = row & 127;
                const int mrow = mask[row];
                if (t != 0 && mrow != 0) {
                    int* wk = (int*)&smem[520];
                    int mi = (tid < TT) ? mask[b*TT + tid] : 0;
                    unsigned long long bal = __ballot(tid < t && mi != 0);
                    if ((tid & 63) == 0) wk[tid >> 6] = __popcll(bal);
                    __syncthreads();
                    int k = wk[0] + wk[1];
                    __syncthreads();
                    const float* g = gum + ((size_t)k*BB + b)*NV;
                    float m = -1e30f;
                    for (int v = tid; v < NV; v += 512) m = fmaxf(m, g[v]);
                    float* red = smem;
                    red[tid] = m; __syncthreads();
                    for (int s = 256; s; s >>= 1) {
                        if (tid < s) red[tid] = fmaxf(red[tid], red[tid+s]);
                        __syncthreads();
                    }
                    if (tid == 0) Mr[row] = red[0];
                    __syncthreads();
                }
            }
        }
        return;
    }

    // =============== round-5 LSTM path (proven 827us fabric) ===============
    float* partials = smem;            // [8][32][36] (also W-stage scratch)
    float* xbuf     = smem + 9216;     // [2][32][33]

    const int u0  = bid*UPB;
    const int w   = tid >> 6;
    const int l   = tid & 63;
    const int rl  = l & 15;
    const int kg  = (l >> 4) * 8;
    const int r4  = (l >> 4) * 4;
    const int gb  = tid >> 3, gul = tid & 7;   // gate mapping (tid<256)

    short8v wH_n0k0, wH_n0k1, wH_n1k0, wH_n1k1;
    short8v wL_n0k0, wL_n0k1, wL_n1k0, wL_n1k1;

    #define BW(WH, WL, KB, CO) do { _Pragma("unroll") \
        for (int j = 0; j < 8; ++j) { \
            float wv2 = partials[((KB)+j)*32 + (CO) + rl]; \
            unsigned short htop = bf16_rne(wv2); \
            WH[j] = (short)htop; \
            WL[j] = (short)bf16_rne(wv2 - bf16f(htop)); \
        } } while(0)

    #define STAGE_BUILD(SRC) do { \
        for (int c = 0; c < 4; ++c) { \
            int k0 = c*128; \
            __syncthreads(); \
            for (int i = tid; i < 4096; i += 512) { \
                int kl = i >> 5, n = i & 31; \
                partials[kl*32 + n] = SRC[(size_t)(k0+kl)*G4 + (size_t)((n>>3)*512 + u0 + (n&7))]; \
            } \
            __syncthreads(); \
            if ((w >> 1) == c) { \
                int kb0 = w*64 - k0 + kg; \
                BW(wH_n0k0, wL_n0k0, kb0,      0); \
                BW(wH_n0k1, wL_n0k1, kb0 + 32, 0); \
                BW(wH_n1k0, wL_n1k0, kb0,     16); \
                BW(wH_n1k1, wL_n1k1, kb0 + 32,16); \
            } \
        } \
        __syncthreads(); } while(0)

    STAGE_BUILD(Whh_e);

    {   // prologue: stage X(0) into xbuf[0]
        for (int i = tid; i < 1024; i += 512) {
            int row2 = i & 31, n = i >> 5;
            xbuf[row2*33 + n] = Xenc[(size_t)((n>>3)*512 + u0 + (n&7))*32 + row2];
        }
        __syncthreads();
    }

    float c_reg = 0.f;

    #define MM6(ACC, AH0, AH1, AL0, AL1, WH0, WH1, WL0, WL1) do { \
        ACC = __builtin_amdgcn_mfma_f32_16x16x32_bf16(AH0, WH0, ACC, 0,0,0); \
        ACC = __builtin_amdgcn_mfma_f32_16x16x32_bf16(AH1, WH1, ACC, 0,0,0); \
        ACC = __builtin_amdgcn_mfma_f32_16x16x32_bf16(AL0, WH0, ACC, 0,0,0); \
        ACC = __builtin_amdgcn_mfma_f32_16x16x32_bf16(AL1, WH1, ACC, 0,0,0); \
        ACC = __builtin_amdgcn_mfma_f32_16x16x32_bf16(AH0, WL0, ACC, 0,0,0); \
        ACC = __builtin_amdgcn_mfma_f32_16x16x32_bf16(AH1, WL1, ACC, 0,0,0); \
    } while(0)

    for (int gstep = 0; gstep < NT_STEPS; ++gstep) {
        const bool enc = gstep < TT;
        const int t = enc ? gstep : gstep - TT;

        f32x4 acc00 = {0,0,0,0}, acc01 = {0,0,0,0}, acc10 = {0,0,0,0}, acc11 = {0,0,0,0};
        if (gstep > 0) {
            const unsigned int* hp = h_pk + (size_t)(gstep & 1)*16384;
            short8v aH_m0k0, aH_m0k1, aH_m1k0, aH_m1k1;
            short8v aL_m0k0, aL_m0k1, aL_m1k0, aL_m1k1;
            #define LOAD_A(AH, AL, MT, KS) do { \
                unsigned int pv[8]; \
                int kbase = w*64 + (KS)*32 + kg; \
                int brow = (MT)*16 + rl; \
                _Pragma("unroll") \
                for (int j = 0; j < 8; ++j) \
                    pv[j] = __hip_atomic_load(&hp[(kbase+j)*32 + brow], \
                                __ATOMIC_RELAXED, __HIP_MEMORY_SCOPE_AGENT); \
                _Pragma("unroll") \
                for (int j = 0; j < 8; ++j) { \
                    AH[j] = (short)(pv[j] & 0xffffu); \
                    AL[j] = (short)(pv[j] >> 16); \
                } } while(0)
            LOAD_A(aH_m0k0, aL_m0k0, 0, 0); LOAD_A(aH_m0k1, aL_m0k1, 0, 1);
            LOAD_A(aH_m1k0, aL_m1k0, 1, 0); LOAD_A(aH_m1k1, aL_m1k1, 1, 1);
            MM6(acc00, aH_m0k0, aH_m0k1, aL_m0k0, aL_m0k1, wH_n0k0, wH_n0k1, wL_n0k0, wL_n0k1);
            MM6(acc01, aH_m0k0, aH_m0k1, aL_m0k0, aL_m0k1, wH_n1k0, wH_n1k1, wL_n1k0, wL_n1k1);
            MM6(acc10, aH_m1k0, aH_m1k1, aL_m1k0, aL_m1k1, wH_n0k0, wH_n0k1, wL_n0k0, wL_n0k1);
            MM6(acc11, aH_m1k0, aH_m1k1, aL_m1k0, aL_m1k1, wH_n1k0, wH_n1k1, wL_n1k0, wL_n1k1);
        }
        #pragma unroll
        for (int j = 0; j < 4; ++j) {
            partials[(w*32 +      r4 + j)*36 +      rl] = acc00[j];
            partials[(w*32 +      r4 + j)*36 + 16 + rl] = acc01[j];
            partials[(w*32 + 16 + r4 + j)*36 +      rl] = acc10[j];
            partials[(w*32 + 16 + r4 + j)*36 + 16 + rl] = acc11[j];
        }
        __syncthreads();

        float hv = 0.f;
        if (tid < 256) {
            float pre[4];
            #pragma unroll
            for (int gg = 0; gg < 4; ++gg) {
                float s = xbuf[(gstep & 1)*1056 + gb*33 + gg*8 + gul];
                #pragma unroll
                for (int ww = 0; ww < 8; ++ww)
                    s += partials[(ww*32 + gb)*36 + gg*8 + gul];
                pre[gg] = s;
            }
            float iv = 1.f/(1.f + expf(-pre[0]));
            float fv = 1.f/(1.f + expf(-pre[1]));
            float gv = tanhf(pre[2]);
            float ov = 1.f/(1.f + expf(-pre[3]));
            c_reg = fmaf(fv, c_reg, iv*gv);
            hv = ov * tanhf(c_reg);
            unsigned short hh = bf16_rne(hv);
            unsigned short hl = bf16_rne(hv - bf16f(hh));
            unsigned int pk = (unsigned int)hh | ((unsigned int)hl << 16);
            __hip_atomic_store(&h_pk[(size_t)((gstep+1) & 1)*16384 + (u0+gul)*32 + gb],
                               pk, __ATOMIC_RELAXED, __HIP_MEMORY_SCOPE_AGENT);
        }
        __syncthreads();                   // vmcnt(0): h_pk stores at coherence pt
        if (gstep < NT_STEPS - 1 && tid == 0)
            __hip_atomic_store(&flags[bid], gstep + 1,
                               __ATOMIC_RELAXED, __HIP_MEMORY_SCOPE_AGENT);
        if (!enc && tid < 256)
            hs[((size_t)t*BB + gb)*HID + u0 + gul] = hv;
        if (gstep == NT_STEPS - 1) break;

        if (gstep == TT - 1) STAGE_BUILD(Whh_d);   // phase switch

        {   // stage X for next step (overlaps the poll wait)
            if (gstep + 1 == TT) {         // one-time decoder-X readiness guard
                if (tid == 0) {
                    while (__hip_atomic_load(decdone, __ATOMIC_RELAXED,
                                             __HIP_MEMORY_SCOPE_AGENT) < NJOB_DEC)
                        __builtin_amdgcn_s_sleep(8);
                }
                __syncthreads();
                __builtin_amdgcn_fence(__ATOMIC_ACQUIRE, "agent");
            }
            int tn = gstep + 1 < TT ? gstep + 1 : gstep + 1 - TT;
            const float* Xt = (gstep + 1 < TT ? Xenc : (const float*)Xdec) + (size_t)tn*G4*BB;
            for (int i = tid; i < 1024; i += 512) {
                int row2 = i & 31, n = i >> 5;
                xbuf[((gstep+1) & 1)*1056 + row2*33 + n] =
                    Xt[(size_t)((n>>3)*512 + u0 + (n&7))*32 + row2];
            }
        }
        if (tid < NB) {
            while (__hip_atomic_load(&flags[tid], __ATOMIC_RELAXED,
                                     __HIP_MEMORY_SCOPE_AGENT) <= gstep) {}
        }
        __syncthreads();
        asm volatile("" ::: "memory");
    }
}

// ---------------- fused: exclk + per-row hnorm + candidate argmax + one-hot --
__global__ __launch_bounds__(256) void cand_write(
        const int* __restrict__ ids, const int* __restrict__ mask,
        const float* __restrict__ gum, const float* __restrict__ rinit,
        const float* __restrict__ hs, const float* __restrict__ Wt,
        const float* __restrict__ fcb, const float* __restrict__ Mr,
        const unsigned int* __restrict__ scal, float* __restrict__ out)
{
    const int row = blockIdx.x, b = row >> 7, t = row & 127;
    const int tid = threadIdx.x;
    __shared__ float red[256];
    __shared__ int idxr[256];
    __shared__ int list[256];
    __shared__ int wcnt[4];
    __shared__ int winsh;

    int win;
    if (mask[row] == 0) {
        win = ids[b*TT + t];
    } else if (t == 0) {
        const float* g  = gum   + (size_t)b*NV;
        const float* r0 = rinit + (size_t)b*NV;
        float bs = -1e30f; int bv = 0x7fffffff;
        for (int v = tid; v < NV; v += 256) {
            float sc = r0[v] + g[v];
            if (sc > bs) { bs = sc; bv = v; }
        }
        red[tid] = bs; idxr[tid] = bv; __syncthreads();
        for (int s = 128; s; s >>= 1) {
            if (tid < s) {
                if (red[tid+s] > red[tid] || (red[tid+s] == red[tid] && idxr[tid+s] < idxr[tid])) {
                    red[tid] = red[tid+s]; idxr[tid] = idxr[tid+s];
                }
            }
            __syncthreads();
        }
        win = idxr[0];
    } else {
        // inline exclusive cumsum k
        int mi = (tid < TT) ? mask[b*TT + tid] : 0;
        unsigned long long bal = __ballot(tid < t && mi != 0);
        if ((tid & 63) == 0) wcnt[tid >> 6] = __popcll(bal);
        __syncthreads();
        const int k = wcnt[0] + wcnt[1];
        __syncthreads();

        const float* g    = gum + ((size_t)k*BB + b)*NV;
        const float* hrow = hs + ((size_t)(t-1)*BB + b)*HID;
        // per-row ||h||^2 (also warms hrow into cache for the dots)
        float hn = 0.f;
        for (int k2 = tid; k2 < HID; k2 += 256) { float x = hrow[k2]; hn = fmaf(x, x, hn); }
        red[tid] = hn; __syncthreads();
        for (int s = 128; s; s >>= 1) {
            if (tid < s) red[tid] += red[tid+s];
            __syncthreads();
        }
        float bound = sqrtf(__uint_as_float(scal[0])) * sqrtf(red[0])
                    + __uint_as_float(scal[1]);
        float thr = Mr[row] - 2.0f*bound*1.05f - 1e-6f;
        __syncthreads();

        float curS = -1e30f; int curV = 0x7fffffff;
        int wv = tid >> 6, lane = tid & 63;
        for (int v0 = 0; v0 < NV; v0 += 256) {
            int v = v0 + tid;
            bool ok = (v < NV) && (g[v] >= thr);
            unsigned long long mb = __ballot(ok);
            if (lane == 0) wcnt[wv] = __popcll(mb);
            __syncthreads();
            int off = 0;
            #pragma unroll
            for (int w = 0; w < 4; w++) if (w < wv) off += wcnt[w];
            int tot = wcnt[0] + wcnt[1] + wcnt[2] + wcnt[3];
            if (ok) {
                int pos = off + __popcll(mb & ((1ull << lane) - 1ull));
                list[pos] = v;
            }
            __syncthreads();
            for (int ci = 0; ci < tot; ci++) {
                int vc = list[ci];
                float p = 0.f;
                for (int k2 = tid; k2 < HID; k2 += 256)
                    p = fmaf(hrow[k2], Wt[(size_t)vc*HID + k2], p);
                red[tid] = p; __syncthreads();
                for (int s = 128; s; s >>= 1) {
                    if (tid < s) red[tid] += red[tid+s];
                    __syncthreads();
                }
                if (tid == 0) {
                    float sc = (red[0] + fcb[vc]) + g[vc];
                    if (sc > curS || (sc == curS && vc < curV)) { curS = sc; curV = vc; }
                }
                __syncthreads();
            }
        }
        if (tid == 0) winsh = curV;
        __syncthreads();
        win = winsh;
    }

    // write one-hot row
    float4* o = (float4*)(out + (size_t)row*NV);
    #pragma unroll
    for (int i = 0; i < 10; i++) {
        int idx = tid + i*256;
        if (idx < 2500) {
            int vb = idx*4;
            float4 val = {0.f, 0.f, 0.f, 0.f};
            if (win >= vb && win < vb+4) ((float*)&val)[win - vb] = 1.0f;
            o[idx] = val;
        }
    }
}

extern "C" void kernel_launch(void* const* d_in, const int* in_sizes, int n_in,
                              void* d_out, int out_size, void* d_ws, size_t ws_size,
                              hipStream_t stream)
{
    const int*   ids   = (const int*)d_in[0];
    const int*   mask  = (const int*)d_in[1];
    const float* eEmb  = (const float*)d_in[2];
    const float* eWih  = (const float*)d_in[3];
    const float* eWhh  = (const float*)d_in[4];
    const float* eB    = (const float*)d_in[5];
    const float* dEmb  = (const float*)d_in[6];
    const float* dWih  = (const float*)d_in[7];
    const float* dWhh  = (const float*)d_in[8];
    const float* dB    = (const float*)d_in[9];
    const float* fcW   = (const float*)d_in[10];
    const float* fcb   = (const float*)d_in[11];
    const float* rinit = (const float*)d_in[12];
    const float* gum   = (const float*)d_in[13];
    float* out = (float*)d_out;

    float* wsf = (float*)d_ws;
    size_t off = 0;
    float* Xenc = wsf + off; off += (size_t)TT*BB*G4;        // [t][col][b]
    float* Xdec = wsf + off; off += (size_t)TD*BB*G4;
    unsigned int* h_pk = (unsigned int*)(wsf + off); off += 2*(size_t)BB*HID;
    float* hs   = wsf + off; off += (size_t)TD*BB*HID;
    float* fcWt = wsf + off; off += (size_t)NV*HID;
    float* Mr   = wsf + off; off += 4096;
    unsigned int* ctl = (unsigned int*)(wsf + off); off += 128;
    unsigned int* scal = ctl;                 // [0..7]
    int* flags   = (int*)(ctl + 8);           // [8..71]
    int* decdone = (int*)(ctl + 72);          // [72]

    hipMemsetAsync(ctl, 0, 128*sizeof(int), stream);

    dim3 gblk(16, 32);
    gemm_x<<<gblk, 256, 0, stream>>>(ids, eEmb, eWih, eB, Xenc, TT*BB);

    lstm_persist<<<GRID_UBER, 512, 0, stream>>>(Xenc, Xdec, eWhh, dWhh,
        h_pk, hs, flags, decdone,
        ids, dEmb, dWih, dB, fcW, fcWt, fcb, mask, gum, Mr, scal);

    cand_write<<<4096, 256, 0, stream>>>(ids, mask, gum, rinit, hs, fcWt, fcb,
                                         Mr, scal, out);
}

// Round 10
// 969.431 us; speedup vs baseline: 2.4825x; 1.0361x over previous
//
#include <hip/hip_runtime.h>
#include <hip/hip_bf16.h>
#include <math.h>

#define BB 32
#define TT 128
#define TD 127
#define EMB 256
#define HID 512
#define G4 2048
#define NV 10000
#define NB 64        // lstm blocks
#define NWK 192      // worker blocks
#define GRID_UBER (NB + NWK)
#define UPB 8
#define NT_STEPS (TT + TD)
#define CAND_CAP 16
#define CAND_DELTA 1.0f

#define NJOB_DEC 512
#define NJOB_TR  313
#define NJOB_WN  20
#define NJOB_RM  4096
#define NJOBS (NJOB_DEC + NJOB_TR + NJOB_WN + NJOB_RM)

typedef __attribute__((ext_vector_type(8))) short short8v;
typedef __attribute__((ext_vector_type(4))) float f32x4;

__device__ __forceinline__ unsigned short bf16_rne(float x){
    unsigned int u = __float_as_uint(x);
    u += 0x7fffu + ((u >> 16) & 1u);
    return (unsigned short)(u >> 16);
}
__device__ __forceinline__ float bf16f(unsigned short h){
    return __uint_as_float(((unsigned int)h) << 16);
}

// ---------------- GEMM (encoder X): X[t][col][b] = embed[tok] @ W + bias ----
__global__ __launch_bounds__(256) void gemm_x(const int* __restrict__ ids,
        const float* __restrict__ embed, const float* __restrict__ W,
        const float* __restrict__ bias, float* __restrict__ X, int M)
{
    __shared__ float As[16][128];
    __shared__ float Bs[16][128];
    __shared__ int toks[128];
    const int tid = threadIdx.x;
    const int m0 = blockIdx.y * 128, n0 = blockIdx.x * 128;
    if (tid < 128) {
        int mr = m0 + tid, tk = 0;
        if (mr < M) { int t = mr >> 5, b = mr & 31; tk = ids[b*TT + t]; }
        toks[tid] = tk;
    }
    __syncthreads();
    float acc[8][8] = {};
    const int ty = tid >> 4, tx = tid & 15;
    for (int kt = 0; kt < EMB; kt += 16) {
        #pragma unroll
        for (int i = 0; i < 2; i++) {
            int idx = tid*2 + i;
            int row = idx >> 2, k4 = (idx & 3)*4;
            float4 a = *(const float4*)&embed[(size_t)toks[row]*EMB + kt + k4];
            As[k4+0][row] = a.x; As[k4+1][row] = a.y; As[k4+2][row] = a.z; As[k4+3][row] = a.w;
        }
        #pragma unroll
        for (int i = 0; i < 2; i++) {
            int idx = tid*2 + i;
            int kr = idx >> 5, c4 = (idx & 31)*4;
            *(float4*)&Bs[kr][c4] = *(const float4*)&W[(size_t)(kt+kr)*G4 + n0 + c4];
        }
        __syncthreads();
        #pragma unroll
        for (int k = 0; k < 16; k++) {
            float a8[8], b8[8];
            #pragma unroll
            for (int i = 0; i < 8; i++) a8[i] = As[k][ty*8+i];
            #pragma unroll
            for (int j = 0; j < 8; j++) b8[j] = Bs[k][tx*8+j];
            #pragma unroll
            for (int i = 0; i < 8; i++) {
                #pragma unroll
                for (int j = 0; j < 8; j++)
                    acc[i][j] = fmaf(a8[i], b8[j], acc[i][j]);
            }
        }
        __syncthreads();
    }
    #pragma unroll
    for (int i = 0; i < 8; i++) {
        int mr = m0 + ty*8 + i;
        if (mr < M) {
            int tt = mr >> 5, bb2 = mr & 31;
            #pragma unroll
            for (int j = 0; j < 8; j++) {
                int nc = n0 + tx*8 + j;
                X[((size_t)tt*G4 + nc)*BB + bb2] = acc[i][j] + bias[nc];
            }
        }
    }
}

// ---------------- UBER kernel: 64 round-5 LSTM blocks + 192 tail workers ----
__global__ __launch_bounds__(512) void lstm_persist(
        const float* __restrict__ Xenc, float* __restrict__ Xdec,
        const float* __restrict__ Whh_e, const float* __restrict__ Whh_d,
        unsigned int* __restrict__ h_pk,   // [2][512][32]
        float* __restrict__ hs,            // [127][32][512]
        int* __restrict__ flags,           // [64]
        int* __restrict__ decdone,         // [1]
        const int* __restrict__ ids, const float* __restrict__ dEmb,
        const float* __restrict__ dWih, const float* __restrict__ dB,
        const float* __restrict__ fcW, float* __restrict__ fcWt,
        const float* __restrict__ fcb, const int* __restrict__ mask,
        const float* __restrict__ gum, const float* __restrict__ rinit,
        float* __restrict__ Mr, unsigned int* __restrict__ scal,
        int* __restrict__ candCnt, int* __restrict__ candList,
        float* __restrict__ outp)
{
    __shared__ float smem[11392];
    const int tid = threadIdx.x;
    const int bid = blockIdx.x;

    if (bid >= NB) {
        // =============== worker blocks: grid-stride job loop ===============
        const int wid = bid - NB;
        for (int job = wid; job < NJOBS; job += NWK) {
            if (job < NJOB_DEC) {
                // ---- decoder-X gemm tile (128m x 128n), 512 threads ----
                const int my = job >> 4, nx = job & 15;
                const int m0 = my*128, n0 = nx*128;
                const int M = TD*BB;
                float* As = smem;              // [16][128]
                float* Bs = smem + 2048;       // [16][128]
                int* toks = (int*)(smem + 4096);
                if (tid < 128) {
                    int mr = m0 + tid, tk = 0;
                    if (mr < M) { int t = mr >> 5, b2 = mr & 31; tk = ids[b2*TT + t]; }
                    toks[tid] = tk;
                }
                __syncthreads();
                float acc[4][8] = {};
                const int ty = tid >> 4, tx = tid & 15;
                for (int kt = 0; kt < EMB; kt += 16) {
                    {
                        int row = tid >> 2, k4 = (tid & 3)*4;
                        float4 a = *(const float4*)&dEmb[(size_t)toks[row]*EMB + kt + k4];
                        As[(k4+0)*128+row] = a.x; As[(k4+1)*128+row] = a.y;
                        As[(k4+2)*128+row] = a.z; As[(k4+3)*128+row] = a.w;
                    }
                    {
                        int kr = tid >> 5, c4 = (tid & 31)*4;
                        *(float4*)&Bs[kr*128 + c4] =
                            *(const float4*)&dWih[(size_t)(kt+kr)*G4 + n0 + c4];
                    }
                    __syncthreads();
                    #pragma unroll
                    for (int k = 0; k < 16; k++) {
                        float a4[4], b8[8];
                        #pragma unroll
                        for (int i = 0; i < 4; i++) a4[i] = As[k*128 + ty*4+i];
                        #pragma unroll
                        for (int j = 0; j < 8; j++) b8[j] = Bs[k*128 + tx*8+j];
                        #pragma unroll
                        for (int i = 0; i < 4; i++) {
                            #pragma unroll
                            for (int j = 0; j < 8; j++)
                                acc[i][j] = fmaf(a4[i], b8[j], acc[i][j]);
                        }
                    }
                    __syncthreads();
                }
                #pragma unroll
                for (int i = 0; i < 4; i++) {
                    int mr = m0 + ty*4 + i;
                    if (mr < M) {
                        int t = mr >> 5, b2 = mr & 31;
                        #pragma unroll
                        for (int j = 0; j < 8; j++) {
                            int nc = n0 + tx*8 + j;
                            Xdec[((size_t)t*G4 + nc)*BB + b2] = acc[i][j] + dB[nc];
                        }
                    }
                }
                __syncthreads();               // all stores acked
                if (tid == 0)                  // release: wbl2 + count
                    __hip_atomic_fetch_add(decdone, 1,
                        __ATOMIC_RELEASE, __HIP_MEMORY_SCOPE_AGENT);
            } else if (job < NJOB_DEC + NJOB_TR) {
                // ---- fc_W transpose strip: 32 v-cols x 512 k ----
                const int v0 = (job - NJOB_DEC)*32;
                float* tile = smem;            // [16][33]
                for (int k0 = 0; k0 < HID; k0 += 16) {
                    {
                        int kk = tid >> 5, vv = tid & 31;
                        int v = v0 + vv;
                        tile[kk*33 + vv] = (v < NV) ? fcW[(size_t)(k0+kk)*NV + v] : 0.f;
                    }
                    __syncthreads();
                    {
                        int vy = tid >> 4, kx = tid & 15;
                        int v = v0 + vy;
                        if (v < NV) fcWt[(size_t)v*HID + k0 + kx] = tile[kx*33 + vy];
                    }
                    __syncthreads();
                }
            } else if (job < NJOB_DEC + NJOB_TR + NJOB_WN) {
                // ---- wnorm: 512 vocab cols ----
                int v = (job - NJOB_DEC - NJOB_TR)*512 + tid;
                if (v < NV) {
                    float s = 0.f;
                    for (int k = 0; k < HID; k++) {
                        float x = fcW[(size_t)k*NV + v]; s = fmaf(x, x, s);
                    }
                    atomicMax(&scal[0], __float_as_uint(s));
                    atomicMax(&scal[1], __float_as_uint(fabsf(fcb[v])));
                }
            } else {
                // ---- row job: finalize easy rows; Mr+candidates+zero for rest
                const int row = job - NJOB_DEC - NJOB_TR - NJOB_WN;
                const int b = row >> 7, t = row & 127;
                const int mrow = mask[row];
                float4* o = (float4*)(outp + (size_t)row*NV);
                if (mrow == 0) {
                    int win = ids[b*TT + t];
                    for (int idx = tid; idx < 2500; idx += 512) {
                        int vb = idx*4;
                        float4 val = {0.f,0.f,0.f,0.f};
                        if (win >= vb && win < vb+4) ((float*)&val)[win-vb] = 1.0f;
                        o[idx] = val;
                    }
                } else if (t == 0) {
                    const float* g  = gum   + (size_t)b*NV;
                    const float* r0 = rinit + (size_t)b*NV;
                    float bs = -1e30f; int bv = 0x7fffffff;
                    for (int v = tid; v < NV; v += 512) {
                        float sc = r0[v] + g[v];
                        if (sc > bs || (sc == bs && v < bv)) { bs = sc; bv = v; }
                    }
                    float* red = smem;
                    int* idxr = (int*)(smem + 512);
                    red[tid] = bs; idxr[tid] = bv; __syncthreads();
                    for (int s = 256; s; s >>= 1) {
                        if (tid < s) {
                            if (red[tid+s] > red[tid] ||
                                (red[tid+s] == red[tid] && idxr[tid+s] < idxr[tid])) {
                                red[tid] = red[tid+s]; idxr[tid] = idxr[tid+s];
                            }
                        }
                        __syncthreads();
                    }
                    int win = idxr[0];
                    __syncthreads();
                    for (int idx = tid; idx < 2500; idx += 512) {
                        int vb = idx*4;
                        float4 val = {0.f,0.f,0.f,0.f};
                        if (win >= vb && win < vb+4) ((float*)&val)[win-vb] = 1.0f;
                        o[idx] = val;
                    }
                } else {
                    int* wk   = (int*)&smem[1024];
                    int* ccnt = (int*)&smem[1040];
                    int mi = (tid < TT) ? mask[b*TT + tid] : 0;
                    unsigned long long bal = __ballot(tid < t && mi != 0);
                    if ((tid & 63) == 0) wk[tid >> 6] = __popcll(bal);
                    if (tid == 0) *ccnt = 0;
                    __syncthreads();
                    const int k = wk[0] + wk[1];
                    const float* g = gum + ((size_t)k*BB + b)*NV;
                    float m = -1e30f;
                    for (int v = tid; v < NV; v += 512) m = fmaxf(m, g[v]);
                    float* red = smem;
                    red[tid] = m; __syncthreads();
                    for (int s = 256; s; s >>= 1) {
                        if (tid < s) red[tid] = fmaxf(red[tid], red[tid+s]);
                        __syncthreads();
                    }
                    const float Mv = red[0];
                    const float thr0 = Mv - CAND_DELTA;
                    // collect candidates (superset of any possible winner set)
                    for (int v = tid; v < NV; v += 512) {
                        if (g[v] >= thr0) {
                            int pos = atomicAdd(ccnt, 1);
                            if (pos < CAND_CAP) candList[row*CAND_CAP + pos] = v;
                        }
                    }
                    // zero output row (winner written later by cand_write)
                    float4 z = {0.f,0.f,0.f,0.f};
                    for (int idx = tid; idx < 2500; idx += 512) o[idx] = z;
                    __syncthreads();
                    if (tid == 0) { candCnt[row] = *ccnt; Mr[row] = Mv; }
                    __syncthreads();
                }
            }
        }
        return;
    }

    // =============== round-5 LSTM path (proven fabric, unchanged) ===============
    float* partials = smem;            // [8][32][36] (also W-stage scratch)
    float* xbuf     = smem + 9216;     // [2][32][33]

    const int u0  = bid*UPB;
    const int w   = tid >> 6;
    const int l   = tid & 63;
    const int rl  = l & 15;
    const int kg  = (l >> 4) * 8;
    const int r4  = (l >> 4) * 4;
    const int gb  = tid >> 3, gul = tid & 7;   // gate mapping (tid<256)

    short8v wH_n0k0, wH_n0k1, wH_n1k0, wH_n1k1;
    short8v wL_n0k0, wL_n0k1, wL_n1k0, wL_n1k1;

    #define BW(WH, WL, KB, CO) do { _Pragma("unroll") \
        for (int j = 0; j < 8; ++j) { \
            float wv2 = partials[((KB)+j)*32 + (CO) + rl]; \
            unsigned short htop = bf16_rne(wv2); \
            WH[j] = (short)htop; \
            WL[j] = (short)bf16_rne(wv2 - bf16f(htop)); \
        } } while(0)

    #define STAGE_BUILD(SRC) do { \
        for (int c = 0; c < 4; ++c) { \
            int k0 = c*128; \
            __syncthreads(); \
            for (int i = tid; i < 4096; i += 512) { \
                int kl = i >> 5, n = i & 31; \
                partials[kl*32 + n] = SRC[(size_t)(k0+kl)*G4 + (size_t)((n>>3)*512 + u0 + (n&7))]; \
            } \
            __syncthreads(); \
            if ((w >> 1) == c) { \
                int kb0 = w*64 - k0 + kg; \
                BW(wH_n0k0, wL_n0k0, kb0,      0); \
                BW(wH_n0k1, wL_n0k1, kb0 + 32, 0); \
                BW(wH_n1k0, wL_n1k0, kb0,     16); \
                BW(wH_n1k1, wL_n1k1, kb0 + 32,16); \
            } \
        } \
        __syncthreads(); } while(0)

    STAGE_BUILD(Whh_e);

    {   // prologue: stage X(0) into xbuf[0]
        for (int i = tid; i < 1024; i += 512) {
            int row2 = i & 31, n = i >> 5;
            xbuf[row2*33 + n] = Xenc[(size_t)((n>>3)*512 + u0 + (n&7))*32 + row2];
        }
        __syncthreads();
    }

    float c_reg = 0.f;

    #define MM6(ACC, AH0, AH1, AL0, AL1, WH0, WH1, WL0, WL1) do { \
        ACC = __builtin_amdgcn_mfma_f32_16x16x32_bf16(AH0, WH0, ACC, 0,0,0); \
        ACC = __builtin_amdgcn_mfma_f32_16x16x32_bf16(AH1, WH1, ACC, 0,0,0); \
        ACC = __builtin_amdgcn_mfma_f32_16x16x32_bf16(AL0, WH0, ACC, 0,0,0); \
        ACC = __builtin_amdgcn_mfma_f32_16x16x32_bf16(AL1, WH1, ACC, 0,0,0); \
        ACC = __builtin_amdgcn_mfma_f32_16x16x32_bf16(AH0, WL0, ACC, 0,0,0); \
        ACC = __builtin_amdgcn_mfma_f32_16x16x32_bf16(AH1, WL1, ACC, 0,0,0); \
    } while(0)

    for (int gstep = 0; gstep < NT_STEPS; ++gstep) {
        const bool enc = gstep < TT;
        const int t = enc ? gstep : gstep - TT;

        f32x4 acc00 = {0,0,0,0}, acc01 = {0,0,0,0}, acc10 = {0,0,0,0}, acc11 = {0,0,0,0};
        if (gstep > 0) {
            const unsigned int* hp = h_pk + (size_t)(gstep & 1)*16384;
            short8v aH_m0k0, aH_m0k1, aH_m1k0, aH_m1k1;
            short8v aL_m0k0, aL_m0k1, aL_m1k0, aL_m1k1;
            #define LOAD_A(AH, AL, MT, KS) do { \
                unsigned int pv[8]; \
                int kbase = w*64 + (KS)*32 + kg; \
                int brow = (MT)*16 + rl; \
                _Pragma("unroll") \
                for (int j = 0; j < 8; ++j) \
                    pv[j] = __hip_atomic_load(&hp[(kbase+j)*32 + brow], \
                                __ATOMIC_RELAXED, __HIP_MEMORY_SCOPE_AGENT); \
                _Pragma("unroll") \
                for (int j = 0; j < 8; ++j) { \
                    AH[j] = (short)(pv[j] & 0xffffu); \
                    AL[j] = (short)(pv[j] >> 16); \
                } } while(0)
            LOAD_A(aH_m0k0, aL_m0k0, 0, 0); LOAD_A(aH_m0k1, aL_m0k1, 0, 1);
            LOAD_A(aH_m1k0, aL_m1k0, 1, 0); LOAD_A(aH_m1k1, aL_m1k1, 1, 1);
            MM6(acc00, aH_m0k0, aH_m0k1, aL_m0k0, aL_m0k1, wH_n0k0, wH_n0k1, wL_n0k0, wL_n0k1);
            MM6(acc01, aH_m0k0, aH_m0k1, aL_m0k0, aL_m0k1, wH_n1k0, wH_n1k1, wL_n1k0, wL_n1k1);
            MM6(acc10, aH_m1k0, aH_m1k1, aL_m1k0, aL_m1k1, wH_n0k0, wH_n0k1, wL_n0k0, wL_n0k1);
            MM6(acc11, aH_m1k0, aH_m1k1, aL_m1k0, aL_m1k1, wH_n1k0, wH_n1k1, wL_n1k0, wL_n1k1);
        }
        #pragma unroll
        for (int j = 0; j < 4; ++j) {
            partials[(w*32 +      r4 + j)*36 +      rl] = acc00[j];
            partials[(w*32 +      r4 + j)*36 + 16 + rl] = acc01[j];
            partials[(w*32 + 16 + r4 + j)*36 +      rl] = acc10[j];
            partials[(w*32 + 16 + r4 + j)*36 + 16 + rl] = acc11[j];
        }
        __syncthreads();

        float hv = 0.f;
        if (tid < 256) {
            float pre[4];
            #pragma unroll
            for (int gg = 0; gg < 4; ++gg) {
                float s = xbuf[(gstep & 1)*1056 + gb*33 + gg*8 + gul];
                #pragma unroll
                for (int ww = 0; ww < 8; ++ww)
                    s += partials[(ww*32 + gb)*36 + gg*8 + gul];
                pre[gg] = s;
            }
            float iv = 1.f/(1.f + expf(-pre[0]));
            float fv = 1.f/(1.f + expf(-pre[1]));
            float gv = tanhf(pre[2]);
            float ov = 1.f/(1.f + expf(-pre[3]));
            c_reg = fmaf(fv, c_reg, iv*gv);
            hv = ov * tanhf(c_reg);
            unsigned short hh = bf16_rne(hv);
            unsigned short hl = bf16_rne(hv - bf16f(hh));
            unsigned int pk = (unsigned int)hh | ((unsigned int)hl << 16);
            __hip_atomic_store(&h_pk[(size_t)((gstep+1) & 1)*16384 + (u0+gul)*32 + gb],
                               pk, __ATOMIC_RELAXED, __HIP_MEMORY_SCOPE_AGENT);
        }
        __syncthreads();                   // vmcnt(0): h_pk stores at coherence pt
        if (gstep < NT_STEPS - 1 && tid == 0)
            __hip_atomic_store(&flags[bid], gstep + 1,
                               __ATOMIC_RELAXED, __HIP_MEMORY_SCOPE_AGENT);
        if (!enc && tid < 256)
            hs[((size_t)t*BB + gb)*HID + u0 + gul] = hv;
        if (gstep == NT_STEPS - 1) break;

        if (gstep == TT - 1) STAGE_BUILD(Whh_d);   // phase switch

        {   // stage X for next step (overlaps the poll wait)
            if (gstep + 1 == TT) {         // one-time decoder-X readiness guard
                if (tid == 0) {
                    while (__hip_atomic_load(decdone, __ATOMIC_RELAXED,
                                             __HIP_MEMORY_SCOPE_AGENT) < NJOB_DEC)
                        __builtin_amdgcn_s_sleep(8);
                }
                __syncthreads();
                __builtin_amdgcn_fence(__ATOMIC_ACQUIRE, "agent");
            }
            int tn = gstep + 1 < TT ? gstep + 1 : gstep + 1 - TT;
            const float* Xt = (gstep + 1 < TT ? Xenc : (const float*)Xdec) + (size_t)tn*G4*BB;
            for (int i = tid; i < 1024; i += 512) {
                int row2 = i & 31, n = i >> 5;
                xbuf[((gstep+1) & 1)*1056 + row2*33 + n] =
                    Xt[(size_t)((n>>3)*512 + u0 + (n&7))*32 + row2];
            }
        }
        if (tid < NB) {
            while (__hip_atomic_load(&flags[tid], __ATOMIC_RELAXED,
                                     __HIP_MEMORY_SCOPE_AGENT) <= gstep) {}
        }
        __syncthreads();
        asm volatile("" ::: "memory");
    }
}

// ------- final: masked t>=1 rows only; candidate dots + single-elem write ----
__global__ __launch_bounds__(256) void cand_write(
        const int* __restrict__ mask, const float* __restrict__ gum,
        const float* __restrict__ hs, const float* __restrict__ Wt,
        const float* __restrict__ fcb, const float* __restrict__ Mr,
        const unsigned int* __restrict__ scal,
        const int* __restrict__ candCnt, const int* __restrict__ candList,
        float* __restrict__ out)
{
    const int row = blockIdx.x, b = row >> 7, t = row & 127;
    if (t == 0 || mask[row] == 0) return;      // handled inside uber kernel
    const int tid = threadIdx.x;
    __shared__ float red[256];
    __shared__ int list[256];
    __shared__ int wcnt[4];

    // inline exclusive cumsum k
    int mi = (tid < TT) ? mask[b*TT + tid] : 0;
    unsigned long long bal = __ballot(tid < t && mi != 0);
    if ((tid & 63) == 0) wcnt[tid >> 6] = __popcll(bal);
    __syncthreads();
    const int k = wcnt[0] + wcnt[1];
    __syncthreads();

    const float* g    = gum + ((size_t)k*BB + b)*NV;
    const float* hrow = hs + ((size_t)(t-1)*BB + b)*HID;
    // per-row ||h||^2
    float hn = 0.f;
    for (int k2 = tid; k2 < HID; k2 += 256) { float x = hrow[k2]; hn = fmaf(x, x, hn); }
    red[tid] = hn; __syncthreads();
    for (int s = 128; s; s >>= 1) {
        if (tid < s) red[tid] += red[tid+s];
        __syncthreads();
    }
    const float Mv = Mr[row];
    float bound = sqrtf(__uint_as_float(scal[0])) * sqrtf(red[0])
                + __uint_as_float(scal[1]);
    float thr = Mv - 2.0f*bound*1.05f - 1e-6f;
    __syncthreads();

    float curS = -1e30f; int curV = 0x7fffffff;
    const int cnt = candCnt[row];

    if (cnt <= CAND_CAP && thr >= Mv - CAND_DELTA) {
        // fast path: candidate list is a superset of all possible winners
        for (int ci = 0; ci < cnt; ci++) {
            int vc = candList[row*CAND_CAP + ci];
            float p = 0.f;
            for (int k2 = tid; k2 < HID; k2 += 256)
                p = fmaf(hrow[k2], Wt[(size_t)vc*HID + k2], p);
            red[tid] = p; __syncthreads();
            for (int s = 128; s; s >>= 1) {
                if (tid < s) red[tid] += red[tid+s];
                __syncthreads();
            }
            if (tid == 0) {
                float sc = (red[0] + fcb[vc]) + g[vc];
                if (sc > curS || (sc == curS && vc < curV)) { curS = sc; curV = vc; }
            }
            __syncthreads();
        }
    } else {
        // fallback: full scan (rare)
        int wv = tid >> 6, lane = tid & 63;
        for (int v0 = 0; v0 < NV; v0 += 256) {
            int v = v0 + tid;
            bool ok = (v < NV) && (g[v] >= thr);
            unsigned long long mb = __ballot(ok);
            if (lane == 0) wcnt[wv] = __popcll(mb);
            __syncthreads();
            int off = 0;
            #pragma unroll
            for (int w = 0; w < 4; w++) if (w < wv) off += wcnt[w];
            int tot = wcnt[0] + wcnt[1] + wcnt[2] + wcnt[3];
            if (ok) {
                int pos = off + __popcll(mb & ((1ull << lane) - 1ull));
                list[pos] = v;
            }
            __syncthreads();
            for (int ci = 0; ci < tot; ci++) {
                int vc = list[ci];
                float p = 0.f;
                for (int k2 = tid; k2 < HID; k2 += 256)
                    p = fmaf(hrow[k2], Wt[(size_t)vc*HID + k2], p);
                red[tid] = p; __syncthreads();
                for (int s = 128; s; s >>= 1) {
                    if (tid < s) red[tid] += red[tid+s];
                    __syncthreads();
                }
                if (tid == 0) {
                    float sc = (red[0] + fcb[vc]) + g[vc];
                    if (sc > curS || (sc == curS && vc < curV)) { curS = sc; curV = vc; }
                }
                __syncthreads();
            }
        }
    }
    if (tid == 0) out[(size_t)row*NV + curV] = 1.0f;   // row pre-zeroed in uber
}

extern "C" void kernel_launch(void* const* d_in, const int* in_sizes, int n_in,
                              void* d_out, int out_size, void* d_ws, size_t ws_size,
                              hipStream_t stream)
{
    const int*   ids   = (const int*)d_in[0];
    const int*   mask  = (const int*)d_in[1];
    const float* eEmb  = (const float*)d_in[2];
    const float* eWih  = (const float*)d_in[3];
    const float* eWhh  = (const float*)d_in[4];
    const float* eB    = (const float*)d_in[5];
    const float* dEmb  = (const float*)d_in[6];
    const float* dWih  = (const float*)d_in[7];
    const float* dWhh  = (const float*)d_in[8];
    const float* dB    = (const float*)d_in[9];
    const float* fcW   = (const float*)d_in[10];
    const float* fcb   = (const float*)d_in[11];
    const float* rinit = (const float*)d_in[12];
    const float* gum   = (const float*)d_in[13];
    float* out = (float*)d_out;

    float* wsf = (float*)d_ws;
    size_t off = 0;
    float* Xenc = wsf + off; off += (size_t)TT*BB*G4;        // [t][col][b]
    float* Xdec = wsf + off; off += (size_t)TD*BB*G4;
    unsigned int* h_pk = (unsigned int*)(wsf + off); off += 2*(size_t)BB*HID;
    float* hs   = wsf + off; off += (size_t)TD*BB*HID;
    float* fcWt = wsf + off; off += (size_t)NV*HID;
    float* Mr   = wsf + off; off += 4096;
    int* candCnt  = (int*)(wsf + off); off += 4096;
    int* candList = (int*)(wsf + off); off += 4096*CAND_CAP;
    unsigned int* ctl = (unsigned int*)(wsf + off); off += 128;
    unsigned int* scal = ctl;                 // [0..7]
    int* flags   = (int*)(ctl + 8);           // [8..71]
    int* decdone = (int*)(ctl + 72);          // [72]

    hipMemsetAsync(ctl, 0, 128*sizeof(int), stream);

    dim3 gblk(16, 32);
    gemm_x<<<gblk, 256, 0, stream>>>(ids, eEmb, eWih, eB, Xenc, TT*BB);

    lstm_persist<<<GRID_UBER, 512, 0, stream>>>(Xenc, Xdec, eWhh, dWhh,
        h_pk, hs, flags, decdone,
        ids, dEmb, dWih, dB, fcW, fcWt, fcb, mask, gum, rinit,
        Mr, scal, candCnt, candList, out);

    cand_write<<<4096, 256, 0, stream>>>(mask, gum, hs, fcWt, fcb,
                                         Mr, scal, candCnt, candList, out);
}